// Round 19
// baseline (303.062 us; speedup 1.0000x reference)
//
#include <hip/hip_runtime.h>
#include <hip/hip_bf16.h>
#include <math.h>

// ---- problem constants ----
static constexpr int LEN = 4096;   // H*W
static constexpr int HN  = 64;     // H
static constexpr int WN  = 64;     // W
static constexpr int NB  = 2;      // batch
static constexpr int DM  = 192;    // d_model
static constexpr int DIM = 384;    // d_inner
static constexpr int NST = 16;     // n_state
static constexpr int DTR = 12;     // dt_rank
static constexpr int KD  = 4;      // directions
static constexpr int NC  = 64;     // scan chunks
static constexpr int CHL = LEN / NC; // 64 elements per chunk

typedef __attribute__((ext_vector_type(8))) short bfrag;
typedef __attribute__((ext_vector_type(4))) float facc;

__device__ __forceinline__ unsigned short f2bf(float x) {
    unsigned int u = __float_as_uint(x);
    return (unsigned short)((u + 0x7FFFu + ((u >> 16) & 1u)) >> 16);
}

// direction k seq-position -> pixel row index (uniform across a wave)
__device__ __forceinline__ int maprow(int k, int gl) {
    int g = (k & 2) ? (LEN - 1 - gl) : gl;
    return (k & 1) ? (((g & 63) << 6) | (g >> 6)) : g;
}

// ---------------------------------------------------------------------------
// weight transform: w (co,ci,3,3) -> wt (t, co, ci)   [ci contiguous, MFMA B]
__global__ void k_wtr(const float* __restrict__ w, float* __restrict__ wt,
                      int cin, int cout, int n)
{
    int idx = blockIdx.x * 256 + threadIdx.x;
    if (idx >= n) return;
    int ci = idx % cin; int r = idx / cin;
    int co = r % cout; int t = r / cout;
    wt[idx] = w[((size_t)(co * cin + ci)) * 9 + t];
}

// pad x_proj_w (4,44,384) -> WX (192,384), rows k*48+c (c<44), zero pad
__global__ void k_wxp(const float* __restrict__ xpw, float* __restrict__ WX)
{
    int idx = blockIdx.x * 256 + threadIdx.x;    // 192*384
    if (idx >= 192 * DIM) return;
    int row = idx / DIM, d = idx - row * DIM;
    int k = row / 48, c = row - k * 48;
    WX[idx] = (c < 44) ? xpw[((size_t)(k * 44 + c)) * DIM + d] : 0.f;
}

// ---------------------------------------------------------------------------
// x (B,64,L) planar -> FN NHWC cols [0,64)
__global__ void k_tr_in(const float* __restrict__ x, float* __restrict__ FN)
{
    __shared__ float t[64][65];
    int b = blockIdx.y, r = blockIdx.x;
    int tid = threadIdx.x;
#pragma unroll
    for (int i = 0; i < 16; ++i) {
        int idx = (i << 8) + tid;
        int c = idx >> 6, xc = idx & 63;
        t[c][xc] = x[((size_t)(b * 64 + c)) * LEN + r * WN + xc];
    }
    __syncthreads();
#pragma unroll
    for (int i = 0; i < 16; ++i) {
        int idx = (i << 8) + tid;
        int px = idx >> 6, c = idx & 63;
        FN[((size_t)(b * LEN + r * WN + px)) * DM + c] = t[c][px];
    }
}

// ---------------------------------------------------------------------------
// MFMA conv3x3, dy-split partials (NHWC, stride=cout). bf16 halo-staged A;
// wave = 32px x 16oc subtile; 3 dx taps via LDS row shifts.
__global__ void __launch_bounds__(256) k_convmf(
    const float* __restrict__ in, int cbuf, int cin, int cout,
    const float* __restrict__ wt2,
    float* __restrict__ part)
{
    __shared__ unsigned short Asb[66][40];
    __shared__ unsigned short Bsb[3][32][40];
    int zz = blockIdx.z;
    int b = zz / 3, s = zz % 3;
    int y0 = blockIdx.x;
    int n0 = blockIdx.y << 5;
    int tid = threadIdx.x;
    int wv = tid >> 6, lane = tid & 63;
    int mb  = (wv & 1) << 5;
    int nbw = (wv >> 1) << 4;
    int lr = lane & 15, lq = lane >> 4;
    int y = y0 + s - 1;
    bool yok = (unsigned)y < (unsigned)HN;
    const float* inb = in + ((size_t)b * LEN + (size_t)y * WN) * cbuf;

    facc acc0 = (facc){0,0,0,0}, acc1 = (facc){0,0,0,0};

    for (int ci0 = 0; ci0 < cin; ci0 += 32) {
#pragma unroll
        for (int it = 0; it < 3; ++it) {
            int fi = (it << 8) + tid;
            if (fi < 528) {
                int px = fi >> 3, c4 = (fi & 7) << 2;
                int xx = px - 1;
                float4 v = make_float4(0.f, 0.f, 0.f, 0.f);
                if (yok && (unsigned)xx < (unsigned)WN)
                    v = *(const float4*)(inb + (size_t)xx * cbuf + ci0 + c4);
                ushort4 u; u.x = f2bf(v.x); u.y = f2bf(v.y); u.z = f2bf(v.z); u.w = f2bf(v.w);
                *(ushort4*)(&Asb[px][c4]) = u;
            }
        }
#pragma unroll
        for (int it = 0; it < 3; ++it) {
            int fi = (it << 8) + tid;
            int dx = fi >> 8; int rem = fi & 255;
            int oc = rem >> 3, c4 = (rem & 7) << 2;
            int t = s * 3 + dx;
            float4 v = *(const float4*)(wt2 + ((size_t)(t * cout + n0 + oc)) * cin + ci0 + c4);
            ushort4 u; u.x = f2bf(v.x); u.y = f2bf(v.y); u.z = f2bf(v.z); u.w = f2bf(v.w);
            *(ushort4*)(&Bsb[dx][oc][c4]) = u;
        }
        __syncthreads();
#pragma unroll
        for (int dx = 0; dx < 3; ++dx) {
            bfrag a0 = *(const bfrag*)(&Asb[mb + lr + dx][lq * 8]);
            bfrag a1 = *(const bfrag*)(&Asb[mb + 16 + lr + dx][lq * 8]);
            bfrag b0 = *(const bfrag*)(&Bsb[dx][nbw + lr][lq * 8]);
            acc0 = __builtin_amdgcn_mfma_f32_16x16x32_bf16(a0, b0, acc0, 0, 0, 0);
            acc1 = __builtin_amdgcn_mfma_f32_16x16x32_bf16(a1, b0, acc1, 0, 0, 0);
        }
        __syncthreads();
    }
    float* pb = part + (((size_t)(s * NB + b) * LEN) + y0 * WN) * cout + n0 + nbw + lr;
#pragma unroll
    for (int r = 0; r < 4; ++r) {
        int px0 = mb + lq * 4 + r;
        pb[(size_t)px0 * cout] = acc0[r];
        pb[(size_t)(px0 + 16) * cout] = acc1[r];
    }
}

// epilogue: sum 3 dy-partials + bias + leakyrelu -> FN NHWC col block
__global__ void k_ep_nhwc(const float* __restrict__ part, const float* __restrict__ bias,
                          float* __restrict__ FN, int co0, float slope)
{
    int idx = blockIdx.x * 256 + threadIdx.x;
    int co = idx & 31, px = idx >> 5;
    const size_t S = (size_t)NB * LEN * 32;
    float v = part[idx] + part[S + idx] + part[2 * S + idx] + bias[co];
    v = v > 0.f ? v : v * slope;
    FN[(size_t)px * DM + co0 + co] = v;
}

// epilogue c5: partials (s,b,L,64) NHWC -> planar out (B,64,L) via LDS transpose
__global__ void k_ep_pl_tr(const float* __restrict__ part, const float* __restrict__ bias,
                           float* __restrict__ out)
{
    __shared__ float t[64][65];
    int b = blockIdx.y, l0 = blockIdx.x << 6;
    int tid = threadIdx.x;
    const size_t S = (size_t)NB * LEN * 64;
#pragma unroll
    for (int i = 0; i < 16; ++i) {
        int idx = (i << 8) + tid;
        int px = idx >> 6, oc = idx & 63;
        size_t o = ((size_t)b * LEN + l0 + px) * 64 + oc;
        t[px][oc] = part[o] + part[S + o] + part[2 * S + o] + bias[oc];
    }
    __syncthreads();
#pragma unroll
    for (int i = 0; i < 16; ++i) {
        int idx = (i << 8) + tid;
        int oc = idx >> 6, px = idx & 63;
        out[((size_t)(b * 64 + oc)) * LEN + l0 + px] = t[px][oc];
    }
}

// ---------------------------------------------------------------------------
// LN statistics only: per pixel mu and rstd over 192 channels of FN
__global__ void k_lnstat(const float* __restrict__ FN, float* __restrict__ MU,
                         float* __restrict__ RS)
{
    int lane = threadIdx.x & 63;
    int pix  = (blockIdx.x << 2) + (threadIdx.x >> 6);
    const float* fp = FN + (size_t)pix * DM;
    float v0 = fp[lane];
    float v1 = fp[lane + 64];
    float v2 = fp[lane + 128];
    float s = v0 + v1 + v2, ss = v0 * v0 + v1 * v1 + v2 * v2;
#pragma unroll
    for (int off = 1; off < 64; off <<= 1) { s += __shfl_xor(s, off); ss += __shfl_xor(ss, off); }
    if (lane == 0) {
        float mu = s * (1.f / 192.f);
        float var = ss * (1.f / 192.f) - mu * mu;
        MU[pix] = mu;
        RS[pix] = rsqrtf(var + 1e-5f);
    }
}

// ---------------------------------------------------------------------------
// bf16 MFMA GEMM core
struct MfTile { facc a00, a01, a10, a11; int mb, nb, lr, lq; };

__device__ __forceinline__ MfTile mf_gemm_core(
    const float* __restrict__ A, int K, const float* __restrict__ Wt,
    int b, int l0, int n0, unsigned short (*Asb)[72], unsigned short (*Bsb)[72])
{
    int tid = threadIdx.x;
    MfTile t;
    t.a00 = (facc){0,0,0,0}; t.a01 = (facc){0,0,0,0};
    t.a10 = (facc){0,0,0,0}; t.a11 = (facc){0,0,0,0};
    int wv = tid >> 6, lane = tid & 63;
    t.mb = (wv & 1) << 5; t.nb = (wv >> 1) << 5;
    t.lr = lane & 15; t.lq = lane >> 4;

    for (int k0 = 0; k0 < K; k0 += 64) {
#pragma unroll
        for (int s = 0; s < 4; ++s) {
            int idx = (s << 8) + tid;
            int row = idx >> 4, c4 = (idx & 15) << 2;
            float4 av = *(const float4*)(A + ((size_t)b * LEN + l0 + row) * K + k0 + c4);
            ushort4 ua; ua.x = f2bf(av.x); ua.y = f2bf(av.y); ua.z = f2bf(av.z); ua.w = f2bf(av.w);
            *(ushort4*)(&Asb[row][c4]) = ua;
            float4 wvv = *(const float4*)(Wt + (size_t)(n0 + row) * K + k0 + c4);
            ushort4 ub; ub.x = f2bf(wvv.x); ub.y = f2bf(wvv.y); ub.z = f2bf(wvv.z); ub.w = f2bf(wvv.w);
            *(ushort4*)(&Bsb[row][c4]) = ub;
        }
        __syncthreads();
#pragma unroll
        for (int kk = 0; kk < 64; kk += 32) {
            bfrag a0 = *(const bfrag*)(&Asb[t.mb + t.lr][kk + t.lq * 8]);
            bfrag a1 = *(const bfrag*)(&Asb[t.mb + 16 + t.lr][kk + t.lq * 8]);
            bfrag b0 = *(const bfrag*)(&Bsb[t.nb + t.lr][kk + t.lq * 8]);
            bfrag b1 = *(const bfrag*)(&Bsb[t.nb + 16 + t.lr][kk + t.lq * 8]);
            t.a00 = __builtin_amdgcn_mfma_f32_16x16x32_bf16(a0, b0, t.a00, 0, 0, 0);
            t.a01 = __builtin_amdgcn_mfma_f32_16x16x32_bf16(a0, b1, t.a01, 0, 0, 0);
            t.a10 = __builtin_amdgcn_mfma_f32_16x16x32_bf16(a1, b0, t.a10, 0, 0, 0);
            t.a11 = __builtin_amdgcn_mfma_f32_16x16x32_bf16(a1, b1, t.a11, 0, 0, 0);
        }
        __syncthreads();
    }
    return t;
}

__device__ __forceinline__ void mf_store(
    facc v, float* __restrict__ Cp, const float* __restrict__ res,
    int b, int l0, int n0, int outC, int lr, int lq)
{
#pragma unroll
    for (int r = 0; r < 4; ++r) {
        int m = lq * 4 + r, n = lr;
        size_t o = ((size_t)b * LEN + l0 + m) * outC + n0 + n;
        float x = v[r];
        if (res) x += res[o];
        Cp[o] = x;
    }
}

__global__ void __launch_bounds__(256) k_gemm_mf(
    const float* __restrict__ A, int K, const float* __restrict__ Wt,
    const float* __restrict__ res, float* __restrict__ Cp, int outC)
{
    __shared__ unsigned short Asb[64][72];
    __shared__ unsigned short Bsb[64][72];
    int b = blockIdx.z, l0 = blockIdx.x << 6, n0 = blockIdx.y << 6;
    MfTile t = mf_gemm_core(A, K, Wt, b, l0, n0, Asb, Bsb);
    mf_store(t.a00, Cp, res, b, l0 + t.mb,      n0 + t.nb,      outC, t.lr, t.lq);
    mf_store(t.a01, Cp, res, b, l0 + t.mb,      n0 + t.nb + 16, outC, t.lr, t.lq);
    mf_store(t.a10, Cp, res, b, l0 + t.mb + 16, n0 + t.nb,      outC, t.lr, t.lq);
    mf_store(t.a11, Cp, res, b, l0 + t.mb + 16, n0 + t.nb + 16, outC, t.lr, t.lq);
}

// fused LN + in_proj MFMA GEMM: A = raw FN; LN applied during staging.
__global__ void __launch_bounds__(256) k_gemm_ipmf(
    const float* __restrict__ A, const float* __restrict__ Wt,
    const float* __restrict__ g, const float* __restrict__ be,
    const float* __restrict__ MU, const float* __restrict__ RS,
    float* __restrict__ XPN, float* __restrict__ ZT)
{
    __shared__ unsigned short Asb[64][72];
    __shared__ unsigned short Bsb[64][72];
    int b = blockIdx.z, l0 = blockIdx.x << 6, n0 = blockIdx.y << 6;
    int tid = threadIdx.x;
    MfTile t;
    t.a00 = (facc){0,0,0,0}; t.a01 = (facc){0,0,0,0};
    t.a10 = (facc){0,0,0,0}; t.a11 = (facc){0,0,0,0};
    int wv = tid >> 6, lane = tid & 63;
    t.mb = (wv & 1) << 5; t.nb = (wv >> 1) << 5;
    t.lr = lane & 15; t.lq = lane >> 4;

    for (int k0 = 0; k0 < DM; k0 += 64) {
#pragma unroll
        for (int s = 0; s < 4; ++s) {
            int idx = (s << 8) + tid;
            int row = idx >> 4, c4 = (idx & 15) << 2;
            size_t pix = (size_t)b * LEN + l0 + row;
            float4 av = *(const float4*)(A + pix * DM + k0 + c4);
            float mu = MU[pix], rs = RS[pix];
            float4 gv = *(const float4*)(g + k0 + c4);
            float4 bv = *(const float4*)(be + k0 + c4);
            av.x = (av.x - mu) * rs * gv.x + bv.x;
            av.y = (av.y - mu) * rs * gv.y + bv.y;
            av.z = (av.z - mu) * rs * gv.z + bv.z;
            av.w = (av.w - mu) * rs * gv.w + bv.w;
            ushort4 ua; ua.x = f2bf(av.x); ua.y = f2bf(av.y); ua.z = f2bf(av.z); ua.w = f2bf(av.w);
            *(ushort4*)(&Asb[row][c4]) = ua;
            float4 wvv = *(const float4*)(Wt + (size_t)(n0 + row) * DM + k0 + c4);
            ushort4 ub; ub.x = f2bf(wvv.x); ub.y = f2bf(wvv.y); ub.z = f2bf(wvv.z); ub.w = f2bf(wvv.w);
            *(ushort4*)(&Bsb[row][c4]) = ub;
        }
        __syncthreads();
#pragma unroll
        for (int kk = 0; kk < 64; kk += 32) {
            bfrag a0 = *(const bfrag*)(&Asb[t.mb + t.lr][kk + t.lq * 8]);
            bfrag a1 = *(const bfrag*)(&Asb[t.mb + 16 + t.lr][kk + t.lq * 8]);
            bfrag b0 = *(const bfrag*)(&Bsb[t.nb + t.lr][kk + t.lq * 8]);
            bfrag b1 = *(const bfrag*)(&Bsb[t.nb + 16 + t.lr][kk + t.lq * 8]);
            t.a00 = __builtin_amdgcn_mfma_f32_16x16x32_bf16(a0, b0, t.a00, 0, 0, 0);
            t.a01 = __builtin_amdgcn_mfma_f32_16x16x32_bf16(a0, b1, t.a01, 0, 0, 0);
            t.a10 = __builtin_amdgcn_mfma_f32_16x16x32_bf16(a1, b0, t.a10, 0, 0, 0);
            t.a11 = __builtin_amdgcn_mfma_f32_16x16x32_bf16(a1, b1, t.a11, 0, 0, 0);
        }
        __syncthreads();
    }
    float* out = (blockIdx.y < 6) ? XPN : ZT;
    int nc = (blockIdx.y < 6) ? n0 : n0 - DIM;
    mf_store(t.a00, out, nullptr, b, l0 + t.mb,      nc + t.nb,      DIM, t.lr, t.lq);
    mf_store(t.a01, out, nullptr, b, l0 + t.mb,      nc + t.nb + 16, DIM, t.lr, t.lq);
    mf_store(t.a10, out, nullptr, b, l0 + t.mb + 16, nc + t.nb,      DIM, t.lr, t.lq);
    mf_store(t.a11, out, nullptr, b, l0 + t.mb + 16, nc + t.nb + 16, DIM, t.lr, t.lq);
}

// ---------------------------------------------------------------------------
// depthwise conv3x3 + SiLU, NHWC in (XPN) -> NHWC out (unh)
__global__ void __launch_bounds__(256) k_dw(
    const float* __restrict__ xpn, const float* __restrict__ w,
    const float* __restrict__ bias, float* __restrict__ unh)
{
    int b = blockIdx.z, cg = blockIdx.y, r = blockIdx.x;
    int lane = threadIdx.x & 63, wv = threadIdx.x >> 6;
    int c = cg * 64 + lane;
    float wl[9];
#pragma unroll
    for (int t = 0; t < 9; ++t) wl[t] = w[c * 9 + t];
    float bv = bias[c];
    const float* base = xpn + (size_t)b * LEN * DIM + c;
    float* ob = unh + (size_t)b * LEN * DIM + c;
#pragma unroll 4
    for (int xi = 0; xi < 16; ++xi) {
        int x = wv * 16 + xi;
        float acc = bv;
#pragma unroll
        for (int dy = 0; dy < 3; ++dy) {
            int ry = r + dy - 1;
            if ((unsigned)ry >= (unsigned)HN) continue;
#pragma unroll
            for (int dx = 0; dx < 3; ++dx) {
                int xx = x + dx - 1;
                if ((unsigned)xx >= (unsigned)WN) continue;
                acc += base[(size_t)(ry * WN + xx) * DIM] * wl[dy * 3 + dx];
            }
        }
        acc = acc / (1.f + __expf(-acc));
        ob[(size_t)(r * WN + x) * DIM] = acc;
    }
}

// ---------------------------------------------------------------------------
// delta = softplus(dtb + CX[:, k*48+0..12] @ dtw[k]^T), pixel-order output
__global__ void __launch_bounds__(384) k_delta(
    const float* __restrict__ CX, const float* __restrict__ dtw,
    const float* __restrict__ dtb, float* __restrict__ dlt)
{
    __shared__ float cs[16][12];
    int b = blockIdx.z, k = blockIdx.y;
    int lp0 = blockIdx.x << 4;
    int tid = threadIdx.x;
    if (tid < 192) {
        int p = tid / 12, r = tid - p * 12;
        cs[p][r] = CX[((size_t)(b * LEN) + lp0 + p) * 192 + k * 48 + r];
    }
    __syncthreads();
    float wt[DTR];
    const float* wp = dtw + ((size_t)(k * DIM) + tid) * DTR;
#pragma unroll
    for (int r = 0; r < DTR; ++r) wt[r] = wp[r];
    float bv = dtb[k * DIM + tid];
    float* dbase = dlt + (((size_t)(b * LEN) + lp0) * KD + k) * DIM + tid;
#pragma unroll
    for (int p = 0; p < 16; ++p) {
        float s = bv;
#pragma unroll
        for (int r = 0; r < DTR; ++r) s += cs[p][r] * wt[r];
        s = (s > 20.f) ? s : __logf(1.f + __expf(s));
        dbase[(size_t)p * KD * DIM] = s;
    }
}

// ---------------------------------------------------------------------------
// chunked scan phase A, state-split: 768 threads; lane pair (d, d+32) holds
// states [0,8) / [8,16). Doubles waves/CU vs 384-thread version.
__global__ void __launch_bounds__(768) k_scan_a(
    const float* __restrict__ unh, const float* __restrict__ CX,
    const float* __restrict__ alog, const float* __restrict__ dlt,
    float* __restrict__ hf, float* __restrict__ pA)
{
    __shared__ float bs[CHL * 16];
    int b = blockIdx.z, k = blockIdx.y, c = blockIdx.x;
    int tid = threadIdx.x;
    int lane = tid & 63;
    int d = ((tid >> 6) << 5) + (lane & 31);
    int half = lane >> 5;
    int nh = half << 3;                     // first state of this half

    for (int i = tid; i < CHL * 16; i += 768) {
        int l = i >> 4, n = i & 15;
        int row = maprow(k, c * CHL + l);
        bs[i] = CX[((size_t)(b * LEN) + row) * 192 + k * 48 + 12 + n];
    }
    __syncthreads();

    float A[8], h[8];
    const float* ap = alog + ((size_t)(k * DIM + d)) * NST;
    float A0 = -__expf(ap[0]);
#pragma unroll
    for (int q = 0; q < 2; ++q) {
        float4 av = *(const float4*)(ap + nh + q * 4);
        A[q * 4]     = -__expf(av.x); A[q * 4 + 1] = -__expf(av.y);
        A[q * 4 + 2] = -__expf(av.z); A[q * 4 + 3] = -__expf(av.w);
    }
    bool geo = true;
#pragma unroll
    for (int i = 0; i < 8; ++i) {
        int n = nh + i;
        geo = geo && (fabsf(A[i] - (n + 1) * A0) <= 1e-4f * (n + 1) * fabsf(A0));
    }
    geo = geo && (bool)__shfl_xor((int)geo, 32);
#pragma unroll
    for (int i = 0; i < 8; ++i) h[i] = 0.f;

    const float* ub = unh + (size_t)b * LEN * DIM + d;
    const float* db = dlt + ((size_t)(b * LEN) * KD + k) * DIM + d;
    size_t base = (((size_t)((b * KD + k) * NC + c)) * NST) * DIM + d;

    float dvA[4], uuA[4], dvB[4], uuB[4], dvC[4], uuC[4];
#pragma unroll
    for (int j = 0; j < 4; ++j) {
        int row = maprow(k, c * CHL + j);
        dvA[j] = db[(size_t)row * KD * DIM];
        uuA[j] = ub[(size_t)row * DIM];
    }
#pragma unroll
    for (int j = 0; j < 4; ++j) {
        int row = maprow(k, c * CHL + 4 + j);
        dvB[j] = db[(size_t)row * KD * DIM];
        uuB[j] = ub[(size_t)row * DIM];
    }

    if (geo) {
        float p0 = 1.f;
        for (int l0 = 0; l0 < CHL; l0 += 4) {
            if (l0 + 8 < CHL) {
#pragma unroll
                for (int j = 0; j < 4; ++j) {
                    int row = maprow(k, c * CHL + l0 + 8 + j);
                    dvC[j] = db[(size_t)row * KD * DIM];
                    uuC[j] = ub[(size_t)row * DIM];
                }
            }
            __builtin_amdgcn_s_setprio(1);
#pragma unroll
            for (int j = 0; j < 4; ++j) {
                float du = dvA[j] * uuA[j];
                const float* bl = bs + (l0 + j) * 16 + nh;
                float qv = __expf(dvA[j] * A0);
                float p2 = qv * qv, p3 = p2 * qv, p4 = p2 * p2;
                float p5 = p4 * qv, p6 = p4 * p2, p7 = p4 * p3, p8 = p4 * p4;
                float m = half ? p8 : 1.f;
                h[0] = (qv * m) * h[0] + du * bl[0];
                h[1] = (p2 * m) * h[1] + du * bl[1];
                h[2] = (p3 * m) * h[2] + du * bl[2];
                h[3] = (p4 * m) * h[3] + du * bl[3];
                h[4] = (p5 * m) * h[4] + du * bl[4];
                h[5] = (p6 * m) * h[5] + du * bl[5];
                h[6] = (p7 * m) * h[6] + du * bl[6];
                h[7] = (p8 * m) * h[7] + du * bl[7];
                p0 *= qv;
            }
            __builtin_amdgcn_s_setprio(0);
#pragma unroll
            for (int j = 0; j < 4; ++j) { dvA[j] = dvB[j]; uuA[j] = uuB[j]; dvB[j] = dvC[j]; uuB[j] = uuC[j]; }
        }
        float q2 = p0 * p0, q3 = q2 * p0, q4 = q2 * q2;
        float q5 = q4 * p0, q6 = q4 * q2, q7 = q4 * q3, q8 = q4 * q4;
        float m0 = half ? q8 : 1.f;
        float Pw[8] = {p0 * m0, q2 * m0, q3 * m0, q4 * m0, q5 * m0, q6 * m0, q7 * m0, q8 * m0};
#pragma unroll
        for (int i = 0; i < 8; ++i) {
            hf[base + (size_t)(nh + i) * DIM] = h[i];
            pA[base + (size_t)(nh + i) * DIM] = Pw[i];
        }
    } else {
        float p[8];
#pragma unroll
        for (int i = 0; i < 8; ++i) p[i] = 1.f;
        for (int l0 = 0; l0 < CHL; l0 += 4) {
            if (l0 + 8 < CHL) {
#pragma unroll
                for (int j = 0; j < 4; ++j) {
                    int row = maprow(k, c * CHL + l0 + 8 + j);
                    dvC[j] = db[(size_t)row * KD * DIM];
                    uuC[j] = ub[(size_t)row * DIM];
                }
            }
#pragma unroll
            for (int j = 0; j < 4; ++j) {
                float du = dvA[j] * uuA[j];
                const float* bl = bs + (l0 + j) * 16 + nh;
#pragma unroll
                for (int i = 0; i < 8; ++i) {
                    float dA = __expf(dvA[j] * A[i]);
                    h[i] = dA * h[i] + du * bl[i];
                    p[i] *= dA;
                }
            }
#pragma unroll
            for (int j = 0; j < 4; ++j) { dvA[j] = dvB[j]; uuA[j] = uuB[j]; dvB[j] = dvC[j]; uuB[j] = uuC[j]; }
        }
#pragma unroll
        for (int i = 0; i < 8; ++i) {
            hf[base + (size_t)(nh + i) * DIM] = h[i];
            pA[base + (size_t)(nh + i) * DIM] = p[i];
        }
    }
}

// phase B: serial carry combine over chunks; hf[c] overwritten with carry-IN.
__global__ void k_scan_b(float* __restrict__ hf, const float* __restrict__ pA)
{
    int s = blockIdx.x * 256 + threadIdx.x;          // NB*KD*NST*DIM = 49152
    int bk = s / (NST * DIM);
    int r  = s - bk * (NST * DIM);
    size_t base = (size_t)bk * NC * NST * DIM + r;
    const size_t cs = (size_t)NST * DIM;
    float car = 0.f;
#pragma unroll 8
    for (int c = 0; c < NC; ++c) {
        float hfc = hf[base + c * cs], pc = pA[base + c * cs];
        hf[base + c * cs] = car;
        car = pc * car + hfc;
    }
}

// phase C, state-split: lane pair (d, d+32) holds states [0,8)/[8,16);
// per-element y = y_lo + shfl_xor(y_hi, 32); half 0 stores.
__global__ void __launch_bounds__(768) k_scan_c(
    const float* __restrict__ unh, const float* __restrict__ CX,
    const float* __restrict__ alog, const float* __restrict__ hf,
    float* __restrict__ dlt)
{
    __shared__ float bs[CHL * 32];
    int b = blockIdx.z, k = blockIdx.y, c = blockIdx.x;
    int tid = threadIdx.x;
    int lane = tid & 63;
    int d = ((tid >> 6) << 5) + (lane & 31);
    int half = lane >> 5;
    int nh = half << 3;

    for (int i = tid; i < CHL * 32; i += 768) {
        int l = i >> 5, n = i & 31;
        int row = maprow(k, c * CHL + l);
        bs[i] = CX[((size_t)(b * LEN) + row) * 192 + k * 48 + 12 + n];
    }
    __syncthreads();

    float A[8], h[8];
    const float* ap = alog + ((size_t)(k * DIM + d)) * NST;
    float A0 = -__expf(ap[0]);
#pragma unroll
    for (int q = 0; q < 2; ++q) {
        float4 av = *(const float4*)(ap + nh + q * 4);
        A[q * 4]     = -__expf(av.x); A[q * 4 + 1] = -__expf(av.y);
        A[q * 4 + 2] = -__expf(av.z); A[q * 4 + 3] = -__expf(av.w);
    }
    bool geo = true;
#pragma unroll
    for (int i = 0; i < 8; ++i) {
        int n = nh + i;
        geo = geo && (fabsf(A[i] - (n + 1) * A0) <= 1e-4f * (n + 1) * fabsf(A0));
    }
    geo = geo && (bool)__shfl_xor((int)geo, 32);
    size_t base = (((size_t)((b * KD + k) * NC + c)) * NST) * DIM + d;
#pragma unroll
    for (int i = 0; i < 8; ++i) h[i] = hf[base + (size_t)(nh + i) * DIM];

    const float* ub = unh + (size_t)b * LEN * DIM + d;
    float* db = dlt + ((size_t)(b * LEN) * KD + k) * DIM + d;

    int rowsA[4], rowsB[4], rowsC[4];
    float dvA[4], uuA[4], dvB[4], uuB[4], dvC[4], uuC[4];
#pragma unroll
    for (int j = 0; j < 4; ++j) {
        rowsA[j] = maprow(k, c * CHL + j);
        dvA[j] = db[(size_t)rowsA[j] * KD * DIM];
        uuA[j] = ub[(size_t)rowsA[j] * DIM];
    }
#pragma unroll
    for (int j = 0; j < 4; ++j) {
        rowsB[j] = maprow(k, c * CHL + 4 + j);
        dvB[j] = db[(size_t)rowsB[j] * KD * DIM];
        uuB[j] = ub[(size_t)rowsB[j] * DIM];
    }

    if (geo) {
        for (int l0 = 0; l0 < CHL; l0 += 4) {
            if (l0 + 8 < CHL) {
#pragma unroll
                for (int j = 0; j < 4; ++j) {
                    rowsC[j] = maprow(k, c * CHL + l0 + 8 + j);
                    dvC[j] = db[(size_t)rowsC[j] * KD * DIM];
                    uuC[j] = ub[(size_t)rowsC[j] * DIM];
                }
            }
            float ys[4];
            __builtin_amdgcn_s_setprio(1);
#pragma unroll
            for (int j = 0; j < 4; ++j) {
                const float* bl = bs + (l0 + j) * 32 + nh;
                float du = dvA[j] * uuA[j];
                float qv = __expf(dvA[j] * A0);
                float p2 = qv * qv, p3 = p2 * qv, p4 = p2 * p2;
                float p5 = p4 * qv, p6 = p4 * p2, p7 = p4 * p3, p8 = p4 * p4;
                float m = half ? p8 : 1.f;
                float y = 0.f;
                h[0] = (qv * m) * h[0] + du * bl[0]; y += h[0] * bl[16];
                h[1] = (p2 * m) * h[1] + du * bl[1]; y += h[1] * bl[17];
                h[2] = (p3 * m) * h[2] + du * bl[2]; y += h[2] * bl[18];
                h[3] = (p4 * m) * h[3] + du * bl[3]; y += h[3] * bl[19];
                h[4] = (p5 * m) * h[4] + du * bl[4]; y += h[4] * bl[20];
                h[5] = (p6 * m) * h[5] + du * bl[5]; y += h[5] * bl[21];
                h[6] = (p7 * m) * h[6] + du * bl[6]; y += h[6] * bl[22];
                h[7] = (p8 * m) * h[7] + du * bl[7]; y += h[7] * bl[23];
                ys[j] = y;
            }
            __builtin_amdgcn_s_setprio(0);
#pragma unroll
            for (int j = 0; j < 4; ++j) ys[j] += __shfl_xor(ys[j], 32);
            if (!half) {
#pragma unroll
                for (int j = 0; j < 4; ++j) db[(size_t)rowsA[j] * KD * DIM] = ys[j];
            }
#pragma unroll
            for (int j = 0; j < 4; ++j) {
                rowsA[j] = rowsB[j]; dvA[j] = dvB[j]; uuA[j] = uuB[j];
                rowsB[j] = rowsC[j]; dvB[j] = dvC[j]; uuB[j] = uuC[j];
            }
        }
    } else {
        for (int l0 = 0; l0 < CHL; l0 += 4) {
            if (l0 + 8 < CHL) {
#pragma unroll
                for (int j = 0; j < 4; ++j) {
                    rowsC[j] = maprow(k, c * CHL + l0 + 8 + j);
                    dvC[j] = db[(size_t)rowsC[j] * KD * DIM];
                    uuC[j] = ub[(size_t)rowsC[j] * DIM];
                }
            }
            float ys[4];
#pragma unroll
            for (int j = 0; j < 4; ++j) {
                const float* bl = bs + (l0 + j) * 32 + nh;
                float du = dvA[j] * uuA[j];
                float y = 0.f;
#pragma unroll
                for (int i = 0; i < 8; ++i) {
                    float dA = __expf(dvA[j] * A[i]);
                    h[i] = dA * h[i] + du * bl[i];
                    y += h[i] * bl[16 + i];
                }
                ys[j] = y;
            }
#pragma unroll
            for (int j = 0; j < 4; ++j) ys[j] += __shfl_xor(ys[j], 32);
            if (!half) {
#pragma unroll
                for (int j = 0; j < 4; ++j) db[(size_t)rowsA[j] * KD * DIM] = ys[j];
            }
#pragma unroll
            for (int j = 0; j < 4; ++j) {
                rowsA[j] = rowsB[j]; dvA[j] = dvB[j]; uuA[j] = uuB[j];
                rowsB[j] = rowsC[j]; dvB[j] = dvC[j]; uuB[j] = uuC[j];
            }
        }
    }
}

// ---------------------------------------------------------------------------
// merge 4 directions + D*u + out-LN + silu(z) gate -> yg NHWC (in-place over unh)
__global__ void k_merge(const float* __restrict__ y4, const float* __restrict__ unh,
                        const float* __restrict__ Ds, const float* __restrict__ ong,
                        const float* __restrict__ onb, const float* __restrict__ zt,
                        float* __restrict__ yg)
{
    int lane = threadIdx.x & 63;
    int pix = (blockIdx.x << 2) + (threadIdx.x >> 6);
    const float* yp = y4 + (size_t)pix * KD * DIM;
    const float* up = unh + (size_t)pix * DIM;
    float v[6]; float s = 0.f, ss = 0.f;
#pragma unroll
    for (int j = 0; j < 6; ++j) {
        int d = lane + (j << 6);
        float y = yp[d] + yp[DIM + d] + yp[2 * DIM + d] + yp[3 * DIM + d];
        float dsum = Ds[d] + Ds[DIM + d] + Ds[2 * DIM + d] + Ds[3 * DIM + d];
        y += dsum * up[d];
        v[j] = y; s += y; ss += y * y;
    }
#pragma unroll
    for (int off = 1; off < 64; off <<= 1) { s += __shfl_xor(s, off); ss += __shfl_xor(ss, off); }
    float mu = s * (1.f / 384.f);
    float var = ss * (1.f / 384.f) - mu * mu;
    float rstd = rsqrtf(var + 1e-5f);
    const float* zp = zt + (size_t)pix * DIM;
    float* op = yg + (size_t)pix * DIM;
#pragma unroll
    for (int j = 0; j < 6; ++j) {
        int d = lane + (j << 6);
        float zz = zp[d];
        float gate = zz / (1.f + __expf(-zz));
        op[d] = ((v[j] - mu) * rstd * ong[d] + onb[d]) * gate;
    }
}

// ---------------------------------------------------------------------------
extern "C" void kernel_launch(void* const* d_in, const int* in_sizes, int n_in,
                              void* d_out, int out_size, void* d_ws, size_t ws_size,
                              hipStream_t stream)
{
    const float* x    = (const float*)d_in[0];
    const float* c1w  = (const float*)d_in[1];  const float* c1b = (const float*)d_in[2];
    const float* c2w  = (const float*)d_in[3];  const float* c2b = (const float*)d_in[4];
    const float* c3w  = (const float*)d_in[5];  const float* c3b = (const float*)d_in[6];
    const float* c4w  = (const float*)d_in[7];  const float* c4b = (const float*)d_in[8];
    const float* c5w  = (const float*)d_in[9];  const float* c5b = (const float*)d_in[10];
    const float* ln1g = (const float*)d_in[11]; const float* ln1b= (const float*)d_in[12];
    const float* ipw  = (const float*)d_in[13];
    const float* dww  = (const float*)d_in[14]; const float* dwb = (const float*)d_in[15];
    const float* xpw  = (const float*)d_in[16];
    const float* dtw  = (const float*)d_in[17]; const float* dtb = (const float*)d_in[18];
    const float* alog = (const float*)d_in[19]; const float* dsv = (const float*)d_in[20];
    const float* ong  = (const float*)d_in[21]; const float* onb = (const float*)d_in[22];
    const float* opw  = (const float*)d_in[23];
    float* out = (float*)d_out;

    float* ws   = (float*)d_ws;
    float* FN   = ws;                   // (B*L,192) NHWC feature     1,572,864
    float* XN   = FN   + 1572864;       // PART / CX
    float* XPN  = XN   + 1572864;       // (B*L,384) xp NHWC; PA after dw
    float* ZT   = XPN  + 3145728;       // (B*L,384) z NHWC
    float* XCNH = ZT   + 3145728;       // (B*L,384) u NHWC; yg in-place
    float* DLT  = XCNH + 3145728;       // (B,L,4,384) delta->y; YN after merge
    float* HF   = DLT  + 12582912;      // carries (bk,c,n,d)         3,145,728
    float* WT14 = HF   + 3145728;       // transformed w c1..c4         129,024
    float* WT5  = WT14 + 129024;        // transformed w c5             110,592
    float* WX   = WT5  + 110592;        // padded x_proj_w (192,384)     73,728
    float* MU   = WX   + 73728;         // LN mean (B*L)                  8,192
    float* RS   = MU   + 8192;          // LN rstd (B*L)                  8,192
    // total 28,628,480 floats = 109.2 MiB
    float* PA = XPN;                    // 3,145,728 = NB*KD*NC*NST*DIM exactly
    float* CX = XN;                     // 1,572,864 = NB*LEN*192 exactly
    float* PART = XN;                   // conv partials (stage A & C)
    float* YN = DLT;                    // out_proj output NHWC (B*L,192)

    // weight transforms  (wt layout: (t, co, ci) for MFMA B operand)
    k_wtr<<<dim3(72),  256, 0, stream>>>(c1w, WT14,          64, 32, 9 * 64 * 32);
    k_wtr<<<dim3(108), 256, 0, stream>>>(c2w, WT14 + 18432,  96, 32, 9 * 96 * 32);
    k_wtr<<<dim3(144), 256, 0, stream>>>(c3w, WT14 + 46080, 128, 32, 9 * 128 * 32);
    k_wtr<<<dim3(180), 256, 0, stream>>>(c4w, WT14 + 82944, 160, 32, 9 * 160 * 32);
    k_wtr<<<dim3(432), 256, 0, stream>>>(c5w, WT5,          192, 64, 9 * 192 * 64);
    k_wxp<<<dim3(288), 256, 0, stream>>>(xpw, WX);

    // stage A: dense conv block (MFMA bf16, halo-staged, dy-split)
    k_tr_in<<<dim3(HN, NB), 256, 0, stream>>>(x, FN);
    k_convmf<<<dim3(64, 1, NB * 3), 256, 0, stream>>>(FN, DM, 64, 32, WT14, PART);
    k_ep_nhwc<<<dim3(1024), 256, 0, stream>>>(PART, c1b, FN, 64, 0.01f);
    k_convmf<<<dim3(64, 1, NB * 3), 256, 0, stream>>>(FN, DM, 96, 32, WT14 + 18432, PART);
    k_ep_nhwc<<<dim3(1024), 256, 0, stream>>>(PART, c2b, FN, 96, 0.01f);
    k_convmf<<<dim3(64, 1, NB * 3), 256, 0, stream>>>(FN, DM, 128, 32, WT14 + 46080, PART);
    k_ep_nhwc<<<dim3(1024), 256, 0, stream>>>(PART, c3b, FN, 128, 0.01f);
    k_convmf<<<dim3(64, 1, NB * 3), 256, 0, stream>>>(FN, DM, 160, 32, WT14 + 82944, PART);
    k_ep_nhwc<<<dim3(1024), 256, 0, stream>>>(PART, c4b, FN, 160, 0.01f);

    // stage B: VSS block (MFMA bf16 GEMMs; LN fused into in_proj staging)
    k_lnstat<<<dim3(NB * LEN / 4), 256, 0, stream>>>(FN, MU, RS);
    k_gemm_ipmf<<<dim3(LEN / 64, 12, NB), 256, 0, stream>>>(FN, ipw, ln1g, ln1b, MU, RS, XPN, ZT);
    k_dw<<<dim3(HN, DIM / 64, NB), 256, 0, stream>>>(XPN, dww, dwb, XCNH);
    k_gemm_mf<<<dim3(LEN / 64, 3, NB), 256, 0, stream>>>(XCNH, DIM, WX, nullptr, CX, 192);
    k_delta<<<dim3(LEN / 16, KD, NB), 384, 0, stream>>>(CX, dtw, dtb, DLT);
    k_scan_a<<<dim3(NC, KD, NB), 768, 0, stream>>>(XCNH, CX, alog, DLT, HF, PA);
    k_scan_b<<<dim3(NB * KD * NST * DIM / 256), 256, 0, stream>>>(HF, PA);
    k_scan_c<<<dim3(NC, KD, NB), 768, 0, stream>>>(XCNH, CX, alog, HF, DLT);
    k_merge<<<dim3(NB * LEN / 4), 256, 0, stream>>>(DLT, XCNH, dsv, ong, onb, ZT, XCNH);
    k_gemm_mf<<<dim3(LEN / 64, 3, NB), 256, 0, stream>>>(XCNH, DIM, opw, FN, YN, DM);

    // stage C: final conv (MFMA bf16, NHWC partials + transpose epilogue)
    k_convmf<<<dim3(64, 2, NB * 3), 256, 0, stream>>>(YN, DM, 192, 64, WT5, PART);
    k_ep_pl_tr<<<dim3(64, NB), 256, 0, stream>>>(PART, c5b, out);
}

// Round 20
// 296.934 us; speedup vs baseline: 1.0206x; 1.0206x over previous
//
#include <hip/hip_runtime.h>
#include <hip/hip_bf16.h>
#include <math.h>

// ---- problem constants ----
static constexpr int LEN = 4096;   // H*W
static constexpr int HN  = 64;     // H
static constexpr int WN  = 64;     // W
static constexpr int NB  = 2;      // batch
static constexpr int DM  = 192;    // d_model
static constexpr int DIM = 384;    // d_inner
static constexpr int NST = 16;     // n_state
static constexpr int DTR = 12;     // dt_rank
static constexpr int KD  = 4;      // directions
static constexpr int NC  = 64;     // scan chunks
static constexpr int CHL = LEN / NC; // 64 elements per chunk

typedef __attribute__((ext_vector_type(8))) short bfrag;
typedef __attribute__((ext_vector_type(4))) float facc;

__device__ __forceinline__ unsigned short f2bf(float x) {
    unsigned int u = __float_as_uint(x);
    return (unsigned short)((u + 0x7FFFu + ((u >> 16) & 1u)) >> 16);
}

// direction k seq-position -> pixel row index (uniform across a wave)
__device__ __forceinline__ int maprow(int k, int gl) {
    int g = (k & 2) ? (LEN - 1 - gl) : gl;
    return (k & 1) ? (((g & 63) << 6) | (g >> 6)) : g;
}

// ---------------------------------------------------------------------------
// weight transform: w (co,ci,3,3) -> wt (t, co, ci)   [ci contiguous, MFMA B]
__global__ void k_wtr(const float* __restrict__ w, float* __restrict__ wt,
                      int cin, int cout, int n)
{
    int idx = blockIdx.x * 256 + threadIdx.x;
    if (idx >= n) return;
    int ci = idx % cin; int r = idx / cin;
    int co = r % cout; int t = r / cout;
    wt[idx] = w[((size_t)(co * cin + ci)) * 9 + t];
}

// pad x_proj_w (4,44,384) -> WX (192,384), rows k*48+c (c<44), zero pad
__global__ void k_wxp(const float* __restrict__ xpw, float* __restrict__ WX)
{
    int idx = blockIdx.x * 256 + threadIdx.x;    // 192*384
    if (idx >= 192 * DIM) return;
    int row = idx / DIM, d = idx - row * DIM;
    int k = row / 48, c = row - k * 48;
    WX[idx] = (c < 44) ? xpw[((size_t)(k * 44 + c)) * DIM + d] : 0.f;
}

// ---------------------------------------------------------------------------
// x (B,64,L) planar -> FN NHWC cols [0,64)
__global__ void k_tr_in(const float* __restrict__ x, float* __restrict__ FN)
{
    __shared__ float t[64][65];
    int b = blockIdx.y, r = blockIdx.x;
    int tid = threadIdx.x;
#pragma unroll
    for (int i = 0; i < 16; ++i) {
        int idx = (i << 8) + tid;
        int c = idx >> 6, xc = idx & 63;
        t[c][xc] = x[((size_t)(b * 64 + c)) * LEN + r * WN + xc];
    }
    __syncthreads();
#pragma unroll
    for (int i = 0; i < 16; ++i) {
        int idx = (i << 8) + tid;
        int px = idx >> 6, c = idx & 63;
        FN[((size_t)(b * LEN + r * WN + px)) * DM + c] = t[c][px];
    }
}

// ---------------------------------------------------------------------------
// MFMA conv3x3, dy-split partials (NHWC, stride=cout). bf16 halo-staged A;
// wave = 32px x 16oc subtile; 3 dx taps via LDS row shifts.
__global__ void __launch_bounds__(256) k_convmf(
    const float* __restrict__ in, int cbuf, int cin, int cout,
    const float* __restrict__ wt2,
    float* __restrict__ part)
{
    __shared__ unsigned short Asb[66][40];
    __shared__ unsigned short Bsb[3][32][40];
    int zz = blockIdx.z;
    int b = zz / 3, s = zz % 3;
    int y0 = blockIdx.x;
    int n0 = blockIdx.y << 5;
    int tid = threadIdx.x;
    int wv = tid >> 6, lane = tid & 63;
    int mb  = (wv & 1) << 5;
    int nbw = (wv >> 1) << 4;
    int lr = lane & 15, lq = lane >> 4;
    int y = y0 + s - 1;
    bool yok = (unsigned)y < (unsigned)HN;
    const float* inb = in + ((size_t)b * LEN + (size_t)y * WN) * cbuf;

    facc acc0 = (facc){0,0,0,0}, acc1 = (facc){0,0,0,0};

    for (int ci0 = 0; ci0 < cin; ci0 += 32) {
#pragma unroll
        for (int it = 0; it < 3; ++it) {
            int fi = (it << 8) + tid;
            if (fi < 528) {
                int px = fi >> 3, c4 = (fi & 7) << 2;
                int xx = px - 1;
                float4 v = make_float4(0.f, 0.f, 0.f, 0.f);
                if (yok && (unsigned)xx < (unsigned)WN)
                    v = *(const float4*)(inb + (size_t)xx * cbuf + ci0 + c4);
                ushort4 u; u.x = f2bf(v.x); u.y = f2bf(v.y); u.z = f2bf(v.z); u.w = f2bf(v.w);
                *(ushort4*)(&Asb[px][c4]) = u;
            }
        }
#pragma unroll
        for (int it = 0; it < 3; ++it) {
            int fi = (it << 8) + tid;
            int dx = fi >> 8; int rem = fi & 255;
            int oc = rem >> 3, c4 = (rem & 7) << 2;
            int t = s * 3 + dx;
            float4 v = *(const float4*)(wt2 + ((size_t)(t * cout + n0 + oc)) * cin + ci0 + c4);
            ushort4 u; u.x = f2bf(v.x); u.y = f2bf(v.y); u.z = f2bf(v.z); u.w = f2bf(v.w);
            *(ushort4*)(&Bsb[dx][oc][c4]) = u;
        }
        __syncthreads();
#pragma unroll
        for (int dx = 0; dx < 3; ++dx) {
            bfrag a0 = *(const bfrag*)(&Asb[mb + lr + dx][lq * 8]);
            bfrag a1 = *(const bfrag*)(&Asb[mb + 16 + lr + dx][lq * 8]);
            bfrag b0 = *(const bfrag*)(&Bsb[dx][nbw + lr][lq * 8]);
            acc0 = __builtin_amdgcn_mfma_f32_16x16x32_bf16(a0, b0, acc0, 0, 0, 0);
            acc1 = __builtin_amdgcn_mfma_f32_16x16x32_bf16(a1, b0, acc1, 0, 0, 0);
        }
        __syncthreads();
    }
    float* pb = part + (((size_t)(s * NB + b) * LEN) + y0 * WN) * cout + n0 + nbw + lr;
#pragma unroll
    for (int r = 0; r < 4; ++r) {
        int px0 = mb + lq * 4 + r;
        pb[(size_t)px0 * cout] = acc0[r];
        pb[(size_t)(px0 + 16) * cout] = acc1[r];
    }
}

// epilogue: sum 3 dy-partials + bias + leakyrelu -> FN NHWC col block
__global__ void k_ep_nhwc(const float* __restrict__ part, const float* __restrict__ bias,
                          float* __restrict__ FN, int co0, float slope)
{
    int idx = blockIdx.x * 256 + threadIdx.x;
    int co = idx & 31, px = idx >> 5;
    const size_t S = (size_t)NB * LEN * 32;
    float v = part[idx] + part[S + idx] + part[2 * S + idx] + bias[co];
    v = v > 0.f ? v : v * slope;
    FN[(size_t)px * DM + co0 + co] = v;
}

// epilogue c5: partials (s,b,L,64) NHWC -> planar out (B,64,L) via LDS transpose
__global__ void k_ep_pl_tr(const float* __restrict__ part, const float* __restrict__ bias,
                           float* __restrict__ out)
{
    __shared__ float t[64][65];
    int b = blockIdx.y, l0 = blockIdx.x << 6;
    int tid = threadIdx.x;
    const size_t S = (size_t)NB * LEN * 64;
#pragma unroll
    for (int i = 0; i < 16; ++i) {
        int idx = (i << 8) + tid;
        int px = idx >> 6, oc = idx & 63;
        size_t o = ((size_t)b * LEN + l0 + px) * 64 + oc;
        t[px][oc] = part[o] + part[S + o] + part[2 * S + o] + bias[oc];
    }
    __syncthreads();
#pragma unroll
    for (int i = 0; i < 16; ++i) {
        int idx = (i << 8) + tid;
        int oc = idx >> 6, px = idx & 63;
        out[((size_t)(b * 64 + oc)) * LEN + l0 + px] = t[px][oc];
    }
}

// ---------------------------------------------------------------------------
// LN statistics only: per pixel mu and rstd over 192 channels of FN
__global__ void k_lnstat(const float* __restrict__ FN, float* __restrict__ MU,
                         float* __restrict__ RS)
{
    int lane = threadIdx.x & 63;
    int pix  = (blockIdx.x << 2) + (threadIdx.x >> 6);
    const float* fp = FN + (size_t)pix * DM;
    float v0 = fp[lane];
    float v1 = fp[lane + 64];
    float v2 = fp[lane + 128];
    float s = v0 + v1 + v2, ss = v0 * v0 + v1 * v1 + v2 * v2;
#pragma unroll
    for (int off = 1; off < 64; off <<= 1) { s += __shfl_xor(s, off); ss += __shfl_xor(ss, off); }
    if (lane == 0) {
        float mu = s * (1.f / 192.f);
        float var = ss * (1.f / 192.f) - mu * mu;
        MU[pix] = mu;
        RS[pix] = rsqrtf(var + 1e-5f);
    }
}

// ---------------------------------------------------------------------------
// bf16 MFMA GEMM core
struct MfTile { facc a00, a01, a10, a11; int mb, nb, lr, lq; };

__device__ __forceinline__ MfTile mf_gemm_core(
    const float* __restrict__ A, int K, const float* __restrict__ Wt,
    int b, int l0, int n0, unsigned short (*Asb)[72], unsigned short (*Bsb)[72])
{
    int tid = threadIdx.x;
    MfTile t;
    t.a00 = (facc){0,0,0,0}; t.a01 = (facc){0,0,0,0};
    t.a10 = (facc){0,0,0,0}; t.a11 = (facc){0,0,0,0};
    int wv = tid >> 6, lane = tid & 63;
    t.mb = (wv & 1) << 5; t.nb = (wv >> 1) << 5;
    t.lr = lane & 15; t.lq = lane >> 4;

    for (int k0 = 0; k0 < K; k0 += 64) {
#pragma unroll
        for (int s = 0; s < 4; ++s) {
            int idx = (s << 8) + tid;
            int row = idx >> 4, c4 = (idx & 15) << 2;
            float4 av = *(const float4*)(A + ((size_t)b * LEN + l0 + row) * K + k0 + c4);
            ushort4 ua; ua.x = f2bf(av.x); ua.y = f2bf(av.y); ua.z = f2bf(av.z); ua.w = f2bf(av.w);
            *(ushort4*)(&Asb[row][c4]) = ua;
            float4 wvv = *(const float4*)(Wt + (size_t)(n0 + row) * K + k0 + c4);
            ushort4 ub; ub.x = f2bf(wvv.x); ub.y = f2bf(wvv.y); ub.z = f2bf(wvv.z); ub.w = f2bf(wvv.w);
            *(ushort4*)(&Bsb[row][c4]) = ub;
        }
        __syncthreads();
#pragma unroll
        for (int kk = 0; kk < 64; kk += 32) {
            bfrag a0 = *(const bfrag*)(&Asb[t.mb + t.lr][kk + t.lq * 8]);
            bfrag a1 = *(const bfrag*)(&Asb[t.mb + 16 + t.lr][kk + t.lq * 8]);
            bfrag b0 = *(const bfrag*)(&Bsb[t.nb + t.lr][kk + t.lq * 8]);
            bfrag b1 = *(const bfrag*)(&Bsb[t.nb + 16 + t.lr][kk + t.lq * 8]);
            t.a00 = __builtin_amdgcn_mfma_f32_16x16x32_bf16(a0, b0, t.a00, 0, 0, 0);
            t.a01 = __builtin_amdgcn_mfma_f32_16x16x32_bf16(a0, b1, t.a01, 0, 0, 0);
            t.a10 = __builtin_amdgcn_mfma_f32_16x16x32_bf16(a1, b0, t.a10, 0, 0, 0);
            t.a11 = __builtin_amdgcn_mfma_f32_16x16x32_bf16(a1, b1, t.a11, 0, 0, 0);
        }
        __syncthreads();
    }
    return t;
}

__device__ __forceinline__ void mf_store(
    facc v, float* __restrict__ Cp, const float* __restrict__ res,
    int b, int l0, int n0, int outC, int lr, int lq)
{
#pragma unroll
    for (int r = 0; r < 4; ++r) {
        int m = lq * 4 + r, n = lr;
        size_t o = ((size_t)b * LEN + l0 + m) * outC + n0 + n;
        float x = v[r];
        if (res) x += res[o];
        Cp[o] = x;
    }
}

__global__ void __launch_bounds__(256) k_gemm_mf(
    const float* __restrict__ A, int K, const float* __restrict__ Wt,
    const float* __restrict__ res, float* __restrict__ Cp, int outC)
{
    __shared__ unsigned short Asb[64][72];
    __shared__ unsigned short Bsb[64][72];
    int b = blockIdx.z, l0 = blockIdx.x << 6, n0 = blockIdx.y << 6;
    MfTile t = mf_gemm_core(A, K, Wt, b, l0, n0, Asb, Bsb);
    mf_store(t.a00, Cp, res, b, l0 + t.mb,      n0 + t.nb,      outC, t.lr, t.lq);
    mf_store(t.a01, Cp, res, b, l0 + t.mb,      n0 + t.nb + 16, outC, t.lr, t.lq);
    mf_store(t.a10, Cp, res, b, l0 + t.mb + 16, n0 + t.nb,      outC, t.lr, t.lq);
    mf_store(t.a11, Cp, res, b, l0 + t.mb + 16, n0 + t.nb + 16, outC, t.lr, t.lq);
}

// fused LN + in_proj MFMA GEMM: A = raw FN; LN applied during staging.
__global__ void __launch_bounds__(256) k_gemm_ipmf(
    const float* __restrict__ A, const float* __restrict__ Wt,
    const float* __restrict__ g, const float* __restrict__ be,
    const float* __restrict__ MU, const float* __restrict__ RS,
    float* __restrict__ XPN, float* __restrict__ ZT)
{
    __shared__ unsigned short Asb[64][72];
    __shared__ unsigned short Bsb[64][72];
    int b = blockIdx.z, l0 = blockIdx.x << 6, n0 = blockIdx.y << 6;
    int tid = threadIdx.x;
    MfTile t;
    t.a00 = (facc){0,0,0,0}; t.a01 = (facc){0,0,0,0};
    t.a10 = (facc){0,0,0,0}; t.a11 = (facc){0,0,0,0};
    int wv = tid >> 6, lane = tid & 63;
    t.mb = (wv & 1) << 5; t.nb = (wv >> 1) << 5;
    t.lr = lane & 15; t.lq = lane >> 4;

    for (int k0 = 0; k0 < DM; k0 += 64) {
#pragma unroll
        for (int s = 0; s < 4; ++s) {
            int idx = (s << 8) + tid;
            int row = idx >> 4, c4 = (idx & 15) << 2;
            size_t pix = (size_t)b * LEN + l0 + row;
            float4 av = *(const float4*)(A + pix * DM + k0 + c4);
            float mu = MU[pix], rs = RS[pix];
            float4 gv = *(const float4*)(g + k0 + c4);
            float4 bv = *(const float4*)(be + k0 + c4);
            av.x = (av.x - mu) * rs * gv.x + bv.x;
            av.y = (av.y - mu) * rs * gv.y + bv.y;
            av.z = (av.z - mu) * rs * gv.z + bv.z;
            av.w = (av.w - mu) * rs * gv.w + bv.w;
            ushort4 ua; ua.x = f2bf(av.x); ua.y = f2bf(av.y); ua.z = f2bf(av.z); ua.w = f2bf(av.w);
            *(ushort4*)(&Asb[row][c4]) = ua;
            float4 wvv = *(const float4*)(Wt + (size_t)(n0 + row) * DM + k0 + c4);
            ushort4 ub; ub.x = f2bf(wvv.x); ub.y = f2bf(wvv.y); ub.z = f2bf(wvv.z); ub.w = f2bf(wvv.w);
            *(ushort4*)(&Bsb[row][c4]) = ub;
        }
        __syncthreads();
#pragma unroll
        for (int kk = 0; kk < 64; kk += 32) {
            bfrag a0 = *(const bfrag*)(&Asb[t.mb + t.lr][kk + t.lq * 8]);
            bfrag a1 = *(const bfrag*)(&Asb[t.mb + 16 + t.lr][kk + t.lq * 8]);
            bfrag b0 = *(const bfrag*)(&Bsb[t.nb + t.lr][kk + t.lq * 8]);
            bfrag b1 = *(const bfrag*)(&Bsb[t.nb + 16 + t.lr][kk + t.lq * 8]);
            t.a00 = __builtin_amdgcn_mfma_f32_16x16x32_bf16(a0, b0, t.a00, 0, 0, 0);
            t.a01 = __builtin_amdgcn_mfma_f32_16x16x32_bf16(a0, b1, t.a01, 0, 0, 0);
            t.a10 = __builtin_amdgcn_mfma_f32_16x16x32_bf16(a1, b0, t.a10, 0, 0, 0);
            t.a11 = __builtin_amdgcn_mfma_f32_16x16x32_bf16(a1, b1, t.a11, 0, 0, 0);
        }
        __syncthreads();
    }
    float* out = (blockIdx.y < 6) ? XPN : ZT;
    int nc = (blockIdx.y < 6) ? n0 : n0 - DIM;
    mf_store(t.a00, out, nullptr, b, l0 + t.mb,      nc + t.nb,      DIM, t.lr, t.lq);
    mf_store(t.a01, out, nullptr, b, l0 + t.mb,      nc + t.nb + 16, DIM, t.lr, t.lq);
    mf_store(t.a10, out, nullptr, b, l0 + t.mb + 16, nc + t.nb,      DIM, t.lr, t.lq);
    mf_store(t.a11, out, nullptr, b, l0 + t.mb + 16, nc + t.nb + 16, DIM, t.lr, t.lq);
}

// ---------------------------------------------------------------------------
// depthwise conv3x3 + SiLU, NHWC in (XPN) -> NHWC out (unh)
__global__ void __launch_bounds__(256) k_dw(
    const float* __restrict__ xpn, const float* __restrict__ w,
    const float* __restrict__ bias, float* __restrict__ unh)
{
    int b = blockIdx.z, cg = blockIdx.y, r = blockIdx.x;
    int lane = threadIdx.x & 63, wv = threadIdx.x >> 6;
    int c = cg * 64 + lane;
    float wl[9];
#pragma unroll
    for (int t = 0; t < 9; ++t) wl[t] = w[c * 9 + t];
    float bv = bias[c];
    const float* base = xpn + (size_t)b * LEN * DIM + c;
    float* ob = unh + (size_t)b * LEN * DIM + c;
#pragma unroll 4
    for (int xi = 0; xi < 16; ++xi) {
        int x = wv * 16 + xi;
        float acc = bv;
#pragma unroll
        for (int dy = 0; dy < 3; ++dy) {
            int ry = r + dy - 1;
            if ((unsigned)ry >= (unsigned)HN) continue;
#pragma unroll
            for (int dx = 0; dx < 3; ++dx) {
                int xx = x + dx - 1;
                if ((unsigned)xx >= (unsigned)WN) continue;
                acc += base[(size_t)(ry * WN + xx) * DIM] * wl[dy * 3 + dx];
            }
        }
        acc = acc / (1.f + __expf(-acc));
        ob[(size_t)(r * WN + x) * DIM] = acc;
    }
}

// ---------------------------------------------------------------------------
// delta = softplus(dtb + CX[:, k*48+0..12] @ dtw[k]^T), pixel-order output
__global__ void __launch_bounds__(384) k_delta(
    const float* __restrict__ CX, const float* __restrict__ dtw,
    const float* __restrict__ dtb, float* __restrict__ dlt)
{
    __shared__ float cs[16][12];
    int b = blockIdx.z, k = blockIdx.y;
    int lp0 = blockIdx.x << 4;
    int tid = threadIdx.x;
    if (tid < 192) {
        int p = tid / 12, r = tid - p * 12;
        cs[p][r] = CX[((size_t)(b * LEN) + lp0 + p) * 192 + k * 48 + r];
    }
    __syncthreads();
    float wt[DTR];
    const float* wp = dtw + ((size_t)(k * DIM) + tid) * DTR;
#pragma unroll
    for (int r = 0; r < DTR; ++r) wt[r] = wp[r];
    float bv = dtb[k * DIM + tid];
    float* dbase = dlt + (((size_t)(b * LEN) + lp0) * KD + k) * DIM + tid;
#pragma unroll
    for (int p = 0; p < 16; ++p) {
        float s = bv;
#pragma unroll
        for (int r = 0; r < DTR; ++r) s += cs[p][r] * wt[r];
        s = (s > 20.f) ? s : __logf(1.f + __expf(s));
        dbase[(size_t)p * KD * DIM] = s;
    }
}

// ---------------------------------------------------------------------------
// chunked scan phase A. thread = d; 16 states in registers; geometric-A fast
// path; depth-2 software pipeline on dv/u loads; setprio around update.
__global__ void __launch_bounds__(384) k_scan_a(
    const float* __restrict__ unh, const float* __restrict__ CX,
    const float* __restrict__ alog, const float* __restrict__ dlt,
    float* __restrict__ hf, float* __restrict__ pA)
{
    __shared__ float bs[CHL * 16];
    int b = blockIdx.z, k = blockIdx.y, c = blockIdx.x;
    int d = threadIdx.x;
    for (int i = threadIdx.x; i < CHL * 16; i += 384) {
        int l = i >> 4, n = i & 15;
        int row = maprow(k, c * CHL + l);
        bs[i] = CX[((size_t)(b * LEN) + row) * 192 + k * 48 + 12 + n];
    }
    __syncthreads();

    float A[16], h[16];
    const float* ap = alog + ((size_t)(k * DIM + d)) * NST;
#pragma unroll
    for (int q = 0; q < 4; ++q) {
        float4 av = *(const float4*)(ap + q * 4);
        A[q * 4]     = -__expf(av.x); A[q * 4 + 1] = -__expf(av.y);
        A[q * 4 + 2] = -__expf(av.z); A[q * 4 + 3] = -__expf(av.w);
    }
    bool geo = true;
#pragma unroll
    for (int n = 1; n < 16; ++n)
        geo = geo && (fabsf(A[n] - (n + 1) * A[0]) <= 1e-4f * (n + 1) * fabsf(A[0]));
#pragma unroll
    for (int n = 0; n < 16; ++n) h[n] = 0.f;

    const float* ub = unh + (size_t)b * LEN * DIM + d;
    const float* db = dlt + ((size_t)(b * LEN) * KD + k) * DIM + d;
    size_t base = (((size_t)((b * KD + k) * NC + c)) * NST) * DIM + d;

    float dvA[4], uuA[4], dvB[4], uuB[4], dvC[4], uuC[4];
#pragma unroll
    for (int j = 0; j < 4; ++j) {
        int row = maprow(k, c * CHL + j);
        dvA[j] = db[(size_t)row * KD * DIM];
        uuA[j] = ub[(size_t)row * DIM];
    }
#pragma unroll
    for (int j = 0; j < 4; ++j) {
        int row = maprow(k, c * CHL + 4 + j);
        dvB[j] = db[(size_t)row * KD * DIM];
        uuB[j] = ub[(size_t)row * DIM];
    }

    if (geo) {
        float A0 = A[0];
        float p0 = 1.f;
        for (int l0 = 0; l0 < CHL; l0 += 4) {
            if (l0 + 8 < CHL) {
#pragma unroll
                for (int j = 0; j < 4; ++j) {
                    int row = maprow(k, c * CHL + l0 + 8 + j);
                    dvC[j] = db[(size_t)row * KD * DIM];
                    uuC[j] = ub[(size_t)row * DIM];
                }
            }
            __builtin_amdgcn_s_setprio(1);
#pragma unroll
            for (int j = 0; j < 4; ++j) {
                float du = dvA[j] * uuA[j];
                const float* bl = bs + (l0 + j) * 16;
                float qv = __expf(dvA[j] * A0);
                float pw = qv;
                h[0] = qv * h[0] + du * bl[0];
#pragma unroll
                for (int n = 1; n < 16; ++n) { pw *= qv; h[n] = pw * h[n] + du * bl[n]; }
                p0 *= qv;
            }
            __builtin_amdgcn_s_setprio(0);
#pragma unroll
            for (int j = 0; j < 4; ++j) { dvA[j] = dvB[j]; uuA[j] = uuB[j]; dvB[j] = dvC[j]; uuB[j] = uuC[j]; }
        }
        float pw = 1.f;
#pragma unroll
        for (int n = 0; n < 16; ++n) {
            pw *= p0;
            hf[base + (size_t)n * DIM] = h[n];
            pA[base + (size_t)n * DIM] = pw;
        }
    } else {
        float p[16];
#pragma unroll
        for (int n = 0; n < 16; ++n) p[n] = 1.f;
        for (int l0 = 0; l0 < CHL; l0 += 4) {
            if (l0 + 8 < CHL) {
#pragma unroll
                for (int j = 0; j < 4; ++j) {
                    int row = maprow(k, c * CHL + l0 + 8 + j);
                    dvC[j] = db[(size_t)row * KD * DIM];
                    uuC[j] = ub[(size_t)row * DIM];
                }
            }
#pragma unroll
            for (int j = 0; j < 4; ++j) {
                float du = dvA[j] * uuA[j];
                const float* bl = bs + (l0 + j) * 16;
#pragma unroll
                for (int n = 0; n < 16; ++n) {
                    float dA = __expf(dvA[j] * A[n]);
                    h[n] = dA * h[n] + du * bl[n];
                    p[n] *= dA;
                }
            }
#pragma unroll
            for (int j = 0; j < 4; ++j) { dvA[j] = dvB[j]; uuA[j] = uuB[j]; dvB[j] = dvC[j]; uuB[j] = uuC[j]; }
        }
#pragma unroll
        for (int n = 0; n < 16; ++n) {
            hf[base + (size_t)n * DIM] = h[n];
            pA[base + (size_t)n * DIM] = p[n];
        }
    }
}

// phase B: serial carry combine over chunks; hf[c] overwritten with carry-IN.
__global__ void k_scan_b(float* __restrict__ hf, const float* __restrict__ pA)
{
    int s = blockIdx.x * 256 + threadIdx.x;          // NB*KD*NST*DIM = 49152
    int bk = s / (NST * DIM);
    int r  = s - bk * (NST * DIM);
    size_t base = (size_t)bk * NC * NST * DIM + r;
    const size_t cs = (size_t)NST * DIM;
    float car = 0.f;
#pragma unroll 8
    for (int c = 0; c < NC; ++c) {
        float hfc = hf[base + c * cs], pc = pA[base + c * cs];
        hf[base + c * cs] = car;
        car = pc * car + hfc;
    }
}

// phase C: re-run chunk from carry-in; geometric-A fast path; y pixel-order
// over delta buffer; depth-2 software pipeline; setprio around update.
__global__ void __launch_bounds__(384) k_scan_c(
    const float* __restrict__ unh, const float* __restrict__ CX,
    const float* __restrict__ alog, const float* __restrict__ hf,
    float* __restrict__ dlt)
{
    __shared__ float bs[CHL * 32];
    int b = blockIdx.z, k = blockIdx.y, c = blockIdx.x;
    int d = threadIdx.x;
    for (int i = threadIdx.x; i < CHL * 32; i += 384) {
        int l = i >> 5, n = i & 31;
        int row = maprow(k, c * CHL + l);
        bs[i] = CX[((size_t)(b * LEN) + row) * 192 + k * 48 + 12 + n];
    }
    __syncthreads();

    float A[16], h[16];
    const float* ap = alog + ((size_t)(k * DIM + d)) * NST;
#pragma unroll
    for (int q = 0; q < 4; ++q) {
        float4 av = *(const float4*)(ap + q * 4);
        A[q * 4]     = -__expf(av.x); A[q * 4 + 1] = -__expf(av.y);
        A[q * 4 + 2] = -__expf(av.z); A[q * 4 + 3] = -__expf(av.w);
    }
    bool geo = true;
#pragma unroll
    for (int n = 1; n < 16; ++n)
        geo = geo && (fabsf(A[n] - (n + 1) * A[0]) <= 1e-4f * (n + 1) * fabsf(A[0]));
    size_t base = (((size_t)((b * KD + k) * NC + c)) * NST) * DIM + d;
#pragma unroll
    for (int n = 0; n < 16; ++n) h[n] = hf[base + (size_t)n * DIM];

    const float* ub = unh + (size_t)b * LEN * DIM + d;
    float* db = dlt + ((size_t)(b * LEN) * KD + k) * DIM + d;

    int rowsA[4], rowsB[4], rowsC[4];
    float dvA[4], uuA[4], dvB[4], uuB[4], dvC[4], uuC[4];
#pragma unroll
    for (int j = 0; j < 4; ++j) {
        rowsA[j] = maprow(k, c * CHL + j);
        dvA[j] = db[(size_t)rowsA[j] * KD * DIM];
        uuA[j] = ub[(size_t)rowsA[j] * DIM];
    }
#pragma unroll
    for (int j = 0; j < 4; ++j) {
        rowsB[j] = maprow(k, c * CHL + 4 + j);
        dvB[j] = db[(size_t)rowsB[j] * KD * DIM];
        uuB[j] = ub[(size_t)rowsB[j] * DIM];
    }

    if (geo) {
        float A0 = A[0];
        for (int l0 = 0; l0 < CHL; l0 += 4) {
            if (l0 + 8 < CHL) {
#pragma unroll
                for (int j = 0; j < 4; ++j) {
                    rowsC[j] = maprow(k, c * CHL + l0 + 8 + j);
                    dvC[j] = db[(size_t)rowsC[j] * KD * DIM];
                    uuC[j] = ub[(size_t)rowsC[j] * DIM];
                }
            }
            float ys[4];
            __builtin_amdgcn_s_setprio(1);
#pragma unroll
            for (int j = 0; j < 4; ++j) {
                const float* bl = bs + (l0 + j) * 32;
                float du = dvA[j] * uuA[j];
                float qv = __expf(dvA[j] * A0);
                float pw = qv;
                h[0] = qv * h[0] + du * bl[0];
                float y = h[0] * bl[16];
#pragma unroll
                for (int n = 1; n < 16; ++n) {
                    pw *= qv;
                    h[n] = pw * h[n] + du * bl[n];
                    y += h[n] * bl[16 + n];
                }
                ys[j] = y;
            }
            __builtin_amdgcn_s_setprio(0);
#pragma unroll
            for (int j = 0; j < 4; ++j) db[(size_t)rowsA[j] * KD * DIM] = ys[j];
#pragma unroll
            for (int j = 0; j < 4; ++j) {
                rowsA[j] = rowsB[j]; dvA[j] = dvB[j]; uuA[j] = uuB[j];
                rowsB[j] = rowsC[j]; dvB[j] = dvC[j]; uuB[j] = uuC[j];
            }
        }
    } else {
        for (int l0 = 0; l0 < CHL; l0 += 4) {
            if (l0 + 8 < CHL) {
#pragma unroll
                for (int j = 0; j < 4; ++j) {
                    rowsC[j] = maprow(k, c * CHL + l0 + 8 + j);
                    dvC[j] = db[(size_t)rowsC[j] * KD * DIM];
                    uuC[j] = ub[(size_t)rowsC[j] * DIM];
                }
            }
            float ys[4];
#pragma unroll
            for (int j = 0; j < 4; ++j) {
                const float* bl = bs + (l0 + j) * 32;
                float du = dvA[j] * uuA[j];
                float y = 0.f;
#pragma unroll
                for (int n = 0; n < 16; ++n) {
                    float dA = __expf(dvA[j] * A[n]);
                    h[n] = dA * h[n] + du * bl[n];
                    y += h[n] * bl[16 + n];
                }
                ys[j] = y;
            }
#pragma unroll
            for (int j = 0; j < 4; ++j) db[(size_t)rowsA[j] * KD * DIM] = ys[j];
#pragma unroll
            for (int j = 0; j < 4; ++j) {
                rowsA[j] = rowsB[j]; dvA[j] = dvB[j]; uuA[j] = uuB[j];
                rowsB[j] = rowsC[j]; dvB[j] = dvC[j]; uuB[j] = uuC[j];
            }
        }
    }
}

// ---------------------------------------------------------------------------
// merge 4 directions + D*u + out-LN + silu(z) gate -> yg NHWC (in-place over unh)
__global__ void k_merge(const float* __restrict__ y4, const float* __restrict__ unh,
                        const float* __restrict__ Ds, const float* __restrict__ ong,
                        const float* __restrict__ onb, const float* __restrict__ zt,
                        float* __restrict__ yg)
{
    int lane = threadIdx.x & 63;
    int pix = (blockIdx.x << 2) + (threadIdx.x >> 6);
    const float* yp = y4 + (size_t)pix * KD * DIM;
    const float* up = unh + (size_t)pix * DIM;
    float v[6]; float s = 0.f, ss = 0.f;
#pragma unroll
    for (int j = 0; j < 6; ++j) {
        int d = lane + (j << 6);
        float y = yp[d] + yp[DIM + d] + yp[2 * DIM + d] + yp[3 * DIM + d];
        float dsum = Ds[d] + Ds[DIM + d] + Ds[2 * DIM + d] + Ds[3 * DIM + d];
        y += dsum * up[d];
        v[j] = y; s += y; ss += y * y;
    }
#pragma unroll
    for (int off = 1; off < 64; off <<= 1) { s += __shfl_xor(s, off); ss += __shfl_xor(ss, off); }
    float mu = s * (1.f / 384.f);
    float var = ss * (1.f / 384.f) - mu * mu;
    float rstd = rsqrtf(var + 1e-5f);
    const float* zp = zt + (size_t)pix * DIM;
    float* op = yg + (size_t)pix * DIM;
#pragma unroll
    for (int j = 0; j < 6; ++j) {
        int d = lane + (j << 6);
        float zz = zp[d];
        float gate = zz / (1.f + __expf(-zz));
        op[d] = ((v[j] - mu) * rstd * ong[d] + onb[d]) * gate;
    }
}

// ---------------------------------------------------------------------------
extern "C" void kernel_launch(void* const* d_in, const int* in_sizes, int n_in,
                              void* d_out, int out_size, void* d_ws, size_t ws_size,
                              hipStream_t stream)
{
    const float* x    = (const float*)d_in[0];
    const float* c1w  = (const float*)d_in[1];  const float* c1b = (const float*)d_in[2];
    const float* c2w  = (const float*)d_in[3];  const float* c2b = (const float*)d_in[4];
    const float* c3w  = (const float*)d_in[5];  const float* c3b = (const float*)d_in[6];
    const float* c4w  = (const float*)d_in[7];  const float* c4b = (const float*)d_in[8];
    const float* c5w  = (const float*)d_in[9];  const float* c5b = (const float*)d_in[10];
    const float* ln1g = (const float*)d_in[11]; const float* ln1b= (const float*)d_in[12];
    const float* ipw  = (const float*)d_in[13];
    const float* dww  = (const float*)d_in[14]; const float* dwb = (const float*)d_in[15];
    const float* xpw  = (const float*)d_in[16];
    const float* dtw  = (const float*)d_in[17]; const float* dtb = (const float*)d_in[18];
    const float* alog = (const float*)d_in[19]; const float* dsv = (const float*)d_in[20];
    const float* ong  = (const float*)d_in[21]; const float* onb = (const float*)d_in[22];
    const float* opw  = (const float*)d_in[23];
    float* out = (float*)d_out;

    float* ws   = (float*)d_ws;
    float* FN   = ws;                   // (B*L,192) NHWC feature     1,572,864
    float* XN   = FN   + 1572864;       // PART / CX
    float* XPN  = XN   + 1572864;       // (B*L,384) xp NHWC; PA after dw
    float* ZT   = XPN  + 3145728;       // (B*L,384) z NHWC
    float* XCNH = ZT   + 3145728;       // (B*L,384) u NHWC; yg in-place
    float* DLT  = XCNH + 3145728;       // (B,L,4,384) delta->y; YN after merge
    float* HF   = DLT  + 12582912;      // carries (bk,c,n,d)         3,145,728
    float* WT14 = HF   + 3145728;       // transformed w c1..c4         129,024
    float* WT5  = WT14 + 129024;        // transformed w c5             110,592
    float* WX   = WT5  + 110592;        // padded x_proj_w (192,384)     73,728
    float* MU   = WX   + 73728;         // LN mean (B*L)                  8,192
    float* RS   = MU   + 8192;          // LN rstd (B*L)                  8,192
    // total 28,628,480 floats = 109.2 MiB
    float* PA = XPN;                    // 3,145,728 = NB*KD*NC*NST*DIM exactly
    float* CX = XN;                     // 1,572,864 = NB*LEN*192 exactly
    float* PART = XN;                   // conv partials (stage A & C)
    float* YN = DLT;                    // out_proj output NHWC (B*L,192)

    // weight transforms  (wt layout: (t, co, ci) for MFMA B operand)
    k_wtr<<<dim3(72),  256, 0, stream>>>(c1w, WT14,          64, 32, 9 * 64 * 32);
    k_wtr<<<dim3(108), 256, 0, stream>>>(c2w, WT14 + 18432,  96, 32, 9 * 96 * 32);
    k_wtr<<<dim3(144), 256, 0, stream>>>(c3w, WT14 + 46080, 128, 32, 9 * 128 * 32);
    k_wtr<<<dim3(180), 256, 0, stream>>>(c4w, WT14 + 82944, 160, 32, 9 * 160 * 32);
    k_wtr<<<dim3(432), 256, 0, stream>>>(c5w, WT5,          192, 64, 9 * 192 * 64);
    k_wxp<<<dim3(288), 256, 0, stream>>>(xpw, WX);

    // stage A: dense conv block (MFMA bf16, halo-staged, dy-split)
    k_tr_in<<<dim3(HN, NB), 256, 0, stream>>>(x, FN);
    k_convmf<<<dim3(64, 1, NB * 3), 256, 0, stream>>>(FN, DM, 64, 32, WT14, PART);
    k_ep_nhwc<<<dim3(1024), 256, 0, stream>>>(PART, c1b, FN, 64, 0.01f);
    k_convmf<<<dim3(64, 1, NB * 3), 256, 0, stream>>>(FN, DM, 96, 32, WT14 + 18432, PART);
    k_ep_nhwc<<<dim3(1024), 256, 0, stream>>>(PART, c2b, FN, 96, 0.01f);
    k_convmf<<<dim3(64, 1, NB * 3), 256, 0, stream>>>(FN, DM, 128, 32, WT14 + 46080, PART);
    k_ep_nhwc<<<dim3(1024), 256, 0, stream>>>(PART, c3b, FN, 128, 0.01f);
    k_convmf<<<dim3(64, 1, NB * 3), 256, 0, stream>>>(FN, DM, 160, 32, WT14 + 82944, PART);
    k_ep_nhwc<<<dim3(1024), 256, 0, stream>>>(PART, c4b, FN, 160, 0.01f);

    // stage B: VSS block (MFMA bf16 GEMMs; LN fused into in_proj staging)
    k_lnstat<<<dim3(NB * LEN / 4), 256, 0, stream>>>(FN, MU, RS);
    k_gemm_ipmf<<<dim3(LEN / 64, 12, NB), 256, 0, stream>>>(FN, ipw, ln1g, ln1b, MU, RS, XPN, ZT);
    k_dw<<<dim3(HN, DIM / 64, NB), 256, 0, stream>>>(XPN, dww, dwb, XCNH);
    k_gemm_mf<<<dim3(LEN / 64, 3, NB), 256, 0, stream>>>(XCNH, DIM, WX, nullptr, CX, 192);
    k_delta<<<dim3(LEN / 16, KD, NB), 384, 0, stream>>>(CX, dtw, dtb, DLT);
    k_scan_a<<<dim3(NC, KD, NB), 384, 0, stream>>>(XCNH, CX, alog, DLT, HF, PA);
    k_scan_b<<<dim3(NB * KD * NST * DIM / 256), 256, 0, stream>>>(HF, PA);
    k_scan_c<<<dim3(NC, KD, NB), 384, 0, stream>>>(XCNH, CX, alog, HF, DLT);
    k_merge<<<dim3(NB * LEN / 4), 256, 0, stream>>>(DLT, XCNH, dsv, ong, onb, ZT, XCNH);
    k_gemm_mf<<<dim3(LEN / 64, 3, NB), 256, 0, stream>>>(XCNH, DIM, opw, FN, YN, DM);

    // stage C: final conv (MFMA bf16, NHWC partials + transpose epilogue)
    k_convmf<<<dim3(64, 2, NB * 3), 256, 0, stream>>>(YN, DM, 192, 64, WT5, PART);
    k_ep_pl_tr<<<dim3(64, NB), 256, 0, stream>>>(PART, c5b, out);
}

// Round 21
// 267.427 us; speedup vs baseline: 1.1333x; 1.1103x over previous
//
#include <hip/hip_runtime.h>
#include <hip/hip_bf16.h>
#include <math.h>

// ---- problem constants ----
static constexpr int LEN = 4096;   // H*W
static constexpr int HN  = 64;     // H
static constexpr int WN  = 64;     // W
static constexpr int NB  = 2;      // batch
static constexpr int DM  = 192;    // d_model
static constexpr int DIM = 384;    // d_inner
static constexpr int NST = 16;     // n_state
static constexpr int DTR = 12;     // dt_rank
static constexpr int KD  = 4;      // directions
static constexpr int NC  = 64;     // scan chunks
static constexpr int CHL = LEN / NC; // 64 elements per chunk

typedef __attribute__((ext_vector_type(8))) short bfrag;
typedef __attribute__((ext_vector_type(4))) float facc;

__device__ __forceinline__ unsigned short f2bf(float x) {
    unsigned int u = __float_as_uint(x);
    return (unsigned short)((u + 0x7FFFu + ((u >> 16) & 1u)) >> 16);
}

// direction k seq-position -> pixel row index (uniform across a wave)
__device__ __forceinline__ int maprow(int k, int gl) {
    int g = (k & 2) ? (LEN - 1 - gl) : gl;
    return (k & 1) ? (((g & 63) << 6) | (g >> 6)) : g;
}

// ---------------------------------------------------------------------------
// weight transform: w (co,ci,3,3) -> wt (t, co, ci)   [ci contiguous, MFMA B]
__global__ void k_wtr(const float* __restrict__ w, float* __restrict__ wt,
                      int cin, int cout, int n)
{
    int idx = blockIdx.x * 256 + threadIdx.x;
    if (idx >= n) return;
    int ci = idx % cin; int r = idx / cin;
    int co = r % cout; int t = r / cout;
    wt[idx] = w[((size_t)(co * cin + ci)) * 9 + t];
}

// pad x_proj_w (4,44,384) -> WX (192,384), rows k*48+c (c<44), zero pad
__global__ void k_wxp(const float* __restrict__ xpw, float* __restrict__ WX)
{
    int idx = blockIdx.x * 256 + threadIdx.x;    // 192*384
    if (idx >= 192 * DIM) return;
    int row = idx / DIM, d = idx - row * DIM;
    int k = row / 48, c = row - k * 48;
    WX[idx] = (c < 44) ? xpw[((size_t)(k * 44 + c)) * DIM + d] : 0.f;
}

// ---------------------------------------------------------------------------
// x (B,64,L) planar -> FN NHWC cols [0,64)
__global__ void k_tr_in(const float* __restrict__ x, float* __restrict__ FN)
{
    __shared__ float t[64][65];
    int b = blockIdx.y, r = blockIdx.x;
    int tid = threadIdx.x;
#pragma unroll
    for (int i = 0; i < 16; ++i) {
        int idx = (i << 8) + tid;
        int c = idx >> 6, xc = idx & 63;
        t[c][xc] = x[((size_t)(b * 64 + c)) * LEN + r * WN + xc];
    }
    __syncthreads();
#pragma unroll
    for (int i = 0; i < 16; ++i) {
        int idx = (i << 8) + tid;
        int px = idx >> 6, c = idx & 63;
        FN[((size_t)(b * LEN + r * WN + px)) * DM + c] = t[c][px];
    }
}

// ---------------------------------------------------------------------------
// MFMA conv3x3, dy-split partials (NHWC, stride=cout). bf16 halo-staged A;
// wave = 32px x 16oc subtile; 3 dx taps via LDS row shifts.
__global__ void __launch_bounds__(256) k_convmf(
    const float* __restrict__ in, int cbuf, int cin, int cout,
    const float* __restrict__ wt2,
    float* __restrict__ part)
{
    __shared__ unsigned short Asb[66][40];
    __shared__ unsigned short Bsb[3][32][40];
    int zz = blockIdx.z;
    int b = zz / 3, s = zz % 3;
    int y0 = blockIdx.x;
    int n0 = blockIdx.y << 5;
    int tid = threadIdx.x;
    int wv = tid >> 6, lane = tid & 63;
    int mb  = (wv & 1) << 5;
    int nbw = (wv >> 1) << 4;
    int lr = lane & 15, lq = lane >> 4;
    int y = y0 + s - 1;
    bool yok = (unsigned)y < (unsigned)HN;
    const float* inb = in + ((size_t)b * LEN + (size_t)y * WN) * cbuf;

    facc acc0 = (facc){0,0,0,0}, acc1 = (facc){0,0,0,0};

    for (int ci0 = 0; ci0 < cin; ci0 += 32) {
#pragma unroll
        for (int it = 0; it < 3; ++it) {
            int fi = (it << 8) + tid;
            if (fi < 528) {
                int px = fi >> 3, c4 = (fi & 7) << 2;
                int xx = px - 1;
                float4 v = make_float4(0.f, 0.f, 0.f, 0.f);
                if (yok && (unsigned)xx < (unsigned)WN)
                    v = *(const float4*)(inb + (size_t)xx * cbuf + ci0 + c4);
                ushort4 u; u.x = f2bf(v.x); u.y = f2bf(v.y); u.z = f2bf(v.z); u.w = f2bf(v.w);
                *(ushort4*)(&Asb[px][c4]) = u;
            }
        }
#pragma unroll
        for (int it = 0; it < 3; ++it) {
            int fi = (it << 8) + tid;
            int dx = fi >> 8; int rem = fi & 255;
            int oc = rem >> 3, c4 = (rem & 7) << 2;
            int t = s * 3 + dx;
            float4 v = *(const float4*)(wt2 + ((size_t)(t * cout + n0 + oc)) * cin + ci0 + c4);
            ushort4 u; u.x = f2bf(v.x); u.y = f2bf(v.y); u.z = f2bf(v.z); u.w = f2bf(v.w);
            *(ushort4*)(&Bsb[dx][oc][c4]) = u;
        }
        __syncthreads();
#pragma unroll
        for (int dx = 0; dx < 3; ++dx) {
            bfrag a0 = *(const bfrag*)(&Asb[mb + lr + dx][lq * 8]);
            bfrag a1 = *(const bfrag*)(&Asb[mb + 16 + lr + dx][lq * 8]);
            bfrag b0 = *(const bfrag*)(&Bsb[dx][nbw + lr][lq * 8]);
            acc0 = __builtin_amdgcn_mfma_f32_16x16x32_bf16(a0, b0, acc0, 0, 0, 0);
            acc1 = __builtin_amdgcn_mfma_f32_16x16x32_bf16(a1, b0, acc1, 0, 0, 0);
        }
        __syncthreads();
    }
    float* pb = part + (((size_t)(s * NB + b) * LEN) + y0 * WN) * cout + n0 + nbw + lr;
#pragma unroll
    for (int r = 0; r < 4; ++r) {
        int px0 = mb + lq * 4 + r;
        pb[(size_t)px0 * cout] = acc0[r];
        pb[(size_t)(px0 + 16) * cout] = acc1[r];
    }
}

// epilogue: sum 3 dy-partials + bias + leakyrelu -> FN NHWC col block
__global__ void k_ep_nhwc(const float* __restrict__ part, const float* __restrict__ bias,
                          float* __restrict__ FN, int co0, float slope)
{
    int idx = blockIdx.x * 256 + threadIdx.x;
    int co = idx & 31, px = idx >> 5;
    const size_t S = (size_t)NB * LEN * 32;
    float v = part[idx] + part[S + idx] + part[2 * S + idx] + bias[co];
    v = v > 0.f ? v : v * slope;
    FN[(size_t)px * DM + co0 + co] = v;
}

// epilogue c5: partials (s,b,L,64) NHWC -> planar out (B,64,L) via LDS transpose
__global__ void k_ep_pl_tr(const float* __restrict__ part, const float* __restrict__ bias,
                           float* __restrict__ out)
{
    __shared__ float t[64][65];
    int b = blockIdx.y, l0 = blockIdx.x << 6;
    int tid = threadIdx.x;
    const size_t S = (size_t)NB * LEN * 64;
#pragma unroll
    for (int i = 0; i < 16; ++i) {
        int idx = (i << 8) + tid;
        int px = idx >> 6, oc = idx & 63;
        size_t o = ((size_t)b * LEN + l0 + px) * 64 + oc;
        t[px][oc] = part[o] + part[S + o] + part[2 * S + o] + bias[oc];
    }
    __syncthreads();
#pragma unroll
    for (int i = 0; i < 16; ++i) {
        int idx = (i << 8) + tid;
        int oc = idx >> 6, px = idx & 63;
        out[((size_t)(b * 64 + oc)) * LEN + l0 + px] = t[px][oc];
    }
}

// ---------------------------------------------------------------------------
// LN statistics only: per pixel mu and rstd over 192 channels of FN
__global__ void k_lnstat(const float* __restrict__ FN, float* __restrict__ MU,
                         float* __restrict__ RS)
{
    int lane = threadIdx.x & 63;
    int pix  = (blockIdx.x << 2) + (threadIdx.x >> 6);
    const float* fp = FN + (size_t)pix * DM;
    float v0 = fp[lane];
    float v1 = fp[lane + 64];
    float v2 = fp[lane + 128];
    float s = v0 + v1 + v2, ss = v0 * v0 + v1 * v1 + v2 * v2;
#pragma unroll
    for (int off = 1; off < 64; off <<= 1) { s += __shfl_xor(s, off); ss += __shfl_xor(ss, off); }
    if (lane == 0) {
        float mu = s * (1.f / 192.f);
        float var = ss * (1.f / 192.f) - mu * mu;
        MU[pix] = mu;
        RS[pix] = rsqrtf(var + 1e-5f);
    }
}

// ---------------------------------------------------------------------------
// bf16 MFMA GEMM core
struct MfTile { facc a00, a01, a10, a11; int mb, nb, lr, lq; };

__device__ __forceinline__ MfTile mf_gemm_core(
    const float* __restrict__ A, int K, const float* __restrict__ Wt,
    int b, int l0, int n0, unsigned short (*Asb)[72], unsigned short (*Bsb)[72])
{
    int tid = threadIdx.x;
    MfTile t;
    t.a00 = (facc){0,0,0,0}; t.a01 = (facc){0,0,0,0};
    t.a10 = (facc){0,0,0,0}; t.a11 = (facc){0,0,0,0};
    int wv = tid >> 6, lane = tid & 63;
    t.mb = (wv & 1) << 5; t.nb = (wv >> 1) << 5;
    t.lr = lane & 15; t.lq = lane >> 4;

    for (int k0 = 0; k0 < K; k0 += 64) {
#pragma unroll
        for (int s = 0; s < 4; ++s) {
            int idx = (s << 8) + tid;
            int row = idx >> 4, c4 = (idx & 15) << 2;
            float4 av = *(const float4*)(A + ((size_t)b * LEN + l0 + row) * K + k0 + c4);
            ushort4 ua; ua.x = f2bf(av.x); ua.y = f2bf(av.y); ua.z = f2bf(av.z); ua.w = f2bf(av.w);
            *(ushort4*)(&Asb[row][c4]) = ua;
            float4 wvv = *(const float4*)(Wt + (size_t)(n0 + row) * K + k0 + c4);
            ushort4 ub; ub.x = f2bf(wvv.x); ub.y = f2bf(wvv.y); ub.z = f2bf(wvv.z); ub.w = f2bf(wvv.w);
            *(ushort4*)(&Bsb[row][c4]) = ub;
        }
        __syncthreads();
#pragma unroll
        for (int kk = 0; kk < 64; kk += 32) {
            bfrag a0 = *(const bfrag*)(&Asb[t.mb + t.lr][kk + t.lq * 8]);
            bfrag a1 = *(const bfrag*)(&Asb[t.mb + 16 + t.lr][kk + t.lq * 8]);
            bfrag b0 = *(const bfrag*)(&Bsb[t.nb + t.lr][kk + t.lq * 8]);
            bfrag b1 = *(const bfrag*)(&Bsb[t.nb + 16 + t.lr][kk + t.lq * 8]);
            t.a00 = __builtin_amdgcn_mfma_f32_16x16x32_bf16(a0, b0, t.a00, 0, 0, 0);
            t.a01 = __builtin_amdgcn_mfma_f32_16x16x32_bf16(a0, b1, t.a01, 0, 0, 0);
            t.a10 = __builtin_amdgcn_mfma_f32_16x16x32_bf16(a1, b0, t.a10, 0, 0, 0);
            t.a11 = __builtin_amdgcn_mfma_f32_16x16x32_bf16(a1, b1, t.a11, 0, 0, 0);
        }
        __syncthreads();
    }
    return t;
}

__device__ __forceinline__ void mf_store(
    facc v, float* __restrict__ Cp, const float* __restrict__ res,
    int b, int l0, int n0, int outC, int lr, int lq)
{
#pragma unroll
    for (int r = 0; r < 4; ++r) {
        int m = lq * 4 + r, n = lr;
        size_t o = ((size_t)b * LEN + l0 + m) * outC + n0 + n;
        float x = v[r];
        if (res) x += res[o];
        Cp[o] = x;
    }
}

__global__ void __launch_bounds__(256) k_gemm_mf(
    const float* __restrict__ A, int K, const float* __restrict__ Wt,
    const float* __restrict__ res, float* __restrict__ Cp, int outC)
{
    __shared__ unsigned short Asb[64][72];
    __shared__ unsigned short Bsb[64][72];
    int b = blockIdx.z, l0 = blockIdx.x << 6, n0 = blockIdx.y << 6;
    MfTile t = mf_gemm_core(A, K, Wt, b, l0, n0, Asb, Bsb);
    mf_store(t.a00, Cp, res, b, l0 + t.mb,      n0 + t.nb,      outC, t.lr, t.lq);
    mf_store(t.a01, Cp, res, b, l0 + t.mb,      n0 + t.nb + 16, outC, t.lr, t.lq);
    mf_store(t.a10, Cp, res, b, l0 + t.mb + 16, n0 + t.nb,      outC, t.lr, t.lq);
    mf_store(t.a11, Cp, res, b, l0 + t.mb + 16, n0 + t.nb + 16, outC, t.lr, t.lq);
}

// fused LN + in_proj MFMA GEMM: A = raw FN; LN applied during staging.
__global__ void __launch_bounds__(256) k_gemm_ipmf(
    const float* __restrict__ A, const float* __restrict__ Wt,
    const float* __restrict__ g, const float* __restrict__ be,
    const float* __restrict__ MU, const float* __restrict__ RS,
    float* __restrict__ XPN, float* __restrict__ ZT)
{
    __shared__ unsigned short Asb[64][72];
    __shared__ unsigned short Bsb[64][72];
    int b = blockIdx.z, l0 = blockIdx.x << 6, n0 = blockIdx.y << 6;
    int tid = threadIdx.x;
    MfTile t;
    t.a00 = (facc){0,0,0,0}; t.a01 = (facc){0,0,0,0};
    t.a10 = (facc){0,0,0,0}; t.a11 = (facc){0,0,0,0};
    int wv = tid >> 6, lane = tid & 63;
    t.mb = (wv & 1) << 5; t.nb = (wv >> 1) << 5;
    t.lr = lane & 15; t.lq = lane >> 4;

    for (int k0 = 0; k0 < DM; k0 += 64) {
#pragma unroll
        for (int s = 0; s < 4; ++s) {
            int idx = (s << 8) + tid;
            int row = idx >> 4, c4 = (idx & 15) << 2;
            size_t pix = (size_t)b * LEN + l0 + row;
            float4 av = *(const float4*)(A + pix * DM + k0 + c4);
            float mu = MU[pix], rs = RS[pix];
            float4 gv = *(const float4*)(g + k0 + c4);
            float4 bv = *(const float4*)(be + k0 + c4);
            av.x = (av.x - mu) * rs * gv.x + bv.x;
            av.y = (av.y - mu) * rs * gv.y + bv.y;
            av.z = (av.z - mu) * rs * gv.z + bv.z;
            av.w = (av.w - mu) * rs * gv.w + bv.w;
            ushort4 ua; ua.x = f2bf(av.x); ua.y = f2bf(av.y); ua.z = f2bf(av.z); ua.w = f2bf(av.w);
            *(ushort4*)(&Asb[row][c4]) = ua;
            float4 wvv = *(const float4*)(Wt + (size_t)(n0 + row) * DM + k0 + c4);
            ushort4 ub; ub.x = f2bf(wvv.x); ub.y = f2bf(wvv.y); ub.z = f2bf(wvv.z); ub.w = f2bf(wvv.w);
            *(ushort4*)(&Bsb[row][c4]) = ub;
        }
        __syncthreads();
#pragma unroll
        for (int kk = 0; kk < 64; kk += 32) {
            bfrag a0 = *(const bfrag*)(&Asb[t.mb + t.lr][kk + t.lq * 8]);
            bfrag a1 = *(const bfrag*)(&Asb[t.mb + 16 + t.lr][kk + t.lq * 8]);
            bfrag b0 = *(const bfrag*)(&Bsb[t.nb + t.lr][kk + t.lq * 8]);
            bfrag b1 = *(const bfrag*)(&Bsb[t.nb + 16 + t.lr][kk + t.lq * 8]);
            t.a00 = __builtin_amdgcn_mfma_f32_16x16x32_bf16(a0, b0, t.a00, 0, 0, 0);
            t.a01 = __builtin_amdgcn_mfma_f32_16x16x32_bf16(a0, b1, t.a01, 0, 0, 0);
            t.a10 = __builtin_amdgcn_mfma_f32_16x16x32_bf16(a1, b0, t.a10, 0, 0, 0);
            t.a11 = __builtin_amdgcn_mfma_f32_16x16x32_bf16(a1, b1, t.a11, 0, 0, 0);
        }
        __syncthreads();
    }
    float* out = (blockIdx.y < 6) ? XPN : ZT;
    int nc = (blockIdx.y < 6) ? n0 : n0 - DIM;
    mf_store(t.a00, out, nullptr, b, l0 + t.mb,      nc + t.nb,      DIM, t.lr, t.lq);
    mf_store(t.a01, out, nullptr, b, l0 + t.mb,      nc + t.nb + 16, DIM, t.lr, t.lq);
    mf_store(t.a10, out, nullptr, b, l0 + t.mb + 16, nc + t.nb,      DIM, t.lr, t.lq);
    mf_store(t.a11, out, nullptr, b, l0 + t.mb + 16, nc + t.nb + 16, DIM, t.lr, t.lq);
}

// ---------------------------------------------------------------------------
// depthwise conv3x3 + SiLU, NHWC in (XPN) -> NHWC out (unh).
// Rolling 3-column register window: 3 loads per output instead of 9.
__global__ void __launch_bounds__(256) k_dw(
    const float* __restrict__ xpn, const float* __restrict__ w,
    const float* __restrict__ bias, float* __restrict__ unh)
{
    int b = blockIdx.z, cg = blockIdx.y, r = blockIdx.x;
    int lane = threadIdx.x & 63, wv = threadIdx.x >> 6;
    int c = cg * 64 + lane;
    float wl[9];
#pragma unroll
    for (int t = 0; t < 9; ++t) wl[t] = w[c * 9 + t];
    float bv = bias[c];
    const float* base = xpn + (size_t)b * LEN * DIM + c;
    float* ob = unh + (size_t)b * LEN * DIM + c;

    bool top = (r == 0), bot = (r == HN - 1);
    int x0 = wv * 16;

    // column loader: 3 dy taps at column xx (0 if out of range)
    auto ldcol = [&](int xx, float* v) {
        if ((unsigned)xx < (unsigned)WN) {
            v[0] = top ? 0.f : base[(size_t)((r - 1) * WN + xx) * DIM];
            v[1] = base[(size_t)(r * WN + xx) * DIM];
            v[2] = bot ? 0.f : base[(size_t)((r + 1) * WN + xx) * DIM];
        } else {
            v[0] = 0.f; v[1] = 0.f; v[2] = 0.f;
        }
    };

    float vm1[3], v0[3], vp1[3];
    ldcol(x0 - 1, vm1);
    ldcol(x0, v0);
#pragma unroll
    for (int xi = 0; xi < 16; ++xi) {
        int x = x0 + xi;
        ldcol(x + 1, vp1);                          // issued before compute
        float acc = bv
            + vm1[0] * wl[0] + v0[0] * wl[1] + vp1[0] * wl[2]
            + vm1[1] * wl[3] + v0[1] * wl[4] + vp1[1] * wl[5]
            + vm1[2] * wl[6] + v0[2] * wl[7] + vp1[2] * wl[8];
        acc = acc / (1.f + __expf(-acc));
        ob[(size_t)(r * WN + x) * DIM] = acc;
#pragma unroll
        for (int dy = 0; dy < 3; ++dy) { vm1[dy] = v0[dy]; v0[dy] = vp1[dy]; }
    }
}

// ---------------------------------------------------------------------------
// delta = softplus(dtb + CX[:, k*48+0..12] @ dtw[k]^T), pixel-order output
__global__ void __launch_bounds__(384) k_delta(
    const float* __restrict__ CX, const float* __restrict__ dtw,
    const float* __restrict__ dtb, float* __restrict__ dlt)
{
    __shared__ float cs[16][12];
    int b = blockIdx.z, k = blockIdx.y;
    int lp0 = blockIdx.x << 4;
    int tid = threadIdx.x;
    if (tid < 192) {
        int p = tid / 12, r = tid - p * 12;
        cs[p][r] = CX[((size_t)(b * LEN) + lp0 + p) * 192 + k * 48 + r];
    }
    __syncthreads();
    float wt[DTR];
    const float* wp = dtw + ((size_t)(k * DIM) + tid) * DTR;
#pragma unroll
    for (int r = 0; r < DTR; ++r) wt[r] = wp[r];
    float bv = dtb[k * DIM + tid];
    float* dbase = dlt + (((size_t)(b * LEN) + lp0) * KD + k) * DIM + tid;
#pragma unroll
    for (int p = 0; p < 16; ++p) {
        float s = bv;
#pragma unroll
        for (int r = 0; r < DTR; ++r) s += cs[p][r] * wt[r];
        s = (s > 20.f) ? s : __logf(1.f + __expf(s));
        dbase[(size_t)p * KD * DIM] = s;
    }
}

// ---------------------------------------------------------------------------
// chunked scan phase A. thread = d; 16 states in registers; geometric-A fast
// path; depth-2 software pipeline on dv/u loads; setprio around update.
__global__ void __launch_bounds__(384) k_scan_a(
    const float* __restrict__ unh, const float* __restrict__ CX,
    const float* __restrict__ alog, const float* __restrict__ dlt,
    float* __restrict__ hf, float* __restrict__ pA)
{
    __shared__ float bs[CHL * 16];
    int b = blockIdx.z, k = blockIdx.y, c = blockIdx.x;
    int d = threadIdx.x;
    for (int i = threadIdx.x; i < CHL * 16; i += 384) {
        int l = i >> 4, n = i & 15;
        int row = maprow(k, c * CHL + l);
        bs[i] = CX[((size_t)(b * LEN) + row) * 192 + k * 48 + 12 + n];
    }
    __syncthreads();

    float A[16], h[16];
    const float* ap = alog + ((size_t)(k * DIM + d)) * NST;
#pragma unroll
    for (int q = 0; q < 4; ++q) {
        float4 av = *(const float4*)(ap + q * 4);
        A[q * 4]     = -__expf(av.x); A[q * 4 + 1] = -__expf(av.y);
        A[q * 4 + 2] = -__expf(av.z); A[q * 4 + 3] = -__expf(av.w);
    }
    bool geo = true;
#pragma unroll
    for (int n = 1; n < 16; ++n)
        geo = geo && (fabsf(A[n] - (n + 1) * A[0]) <= 1e-4f * (n + 1) * fabsf(A[0]));
#pragma unroll
    for (int n = 0; n < 16; ++n) h[n] = 0.f;

    const float* ub = unh + (size_t)b * LEN * DIM + d;
    const float* db = dlt + ((size_t)(b * LEN) * KD + k) * DIM + d;
    size_t base = (((size_t)((b * KD + k) * NC + c)) * NST) * DIM + d;

    float dvA[4], uuA[4], dvB[4], uuB[4], dvC[4], uuC[4];
#pragma unroll
    for (int j = 0; j < 4; ++j) {
        int row = maprow(k, c * CHL + j);
        dvA[j] = db[(size_t)row * KD * DIM];
        uuA[j] = ub[(size_t)row * DIM];
    }
#pragma unroll
    for (int j = 0; j < 4; ++j) {
        int row = maprow(k, c * CHL + 4 + j);
        dvB[j] = db[(size_t)row * KD * DIM];
        uuB[j] = ub[(size_t)row * DIM];
    }

    if (geo) {
        float A0 = A[0];
        float p0 = 1.f;
        for (int l0 = 0; l0 < CHL; l0 += 4) {
            if (l0 + 8 < CHL) {
#pragma unroll
                for (int j = 0; j < 4; ++j) {
                    int row = maprow(k, c * CHL + l0 + 8 + j);
                    dvC[j] = db[(size_t)row * KD * DIM];
                    uuC[j] = ub[(size_t)row * DIM];
                }
            }
            __builtin_amdgcn_s_setprio(1);
#pragma unroll
            for (int j = 0; j < 4; ++j) {
                float du = dvA[j] * uuA[j];
                const float* bl = bs + (l0 + j) * 16;
                float qv = __expf(dvA[j] * A0);
                float pw = qv;
                h[0] = qv * h[0] + du * bl[0];
#pragma unroll
                for (int n = 1; n < 16; ++n) { pw *= qv; h[n] = pw * h[n] + du * bl[n]; }
                p0 *= qv;
            }
            __builtin_amdgcn_s_setprio(0);
#pragma unroll
            for (int j = 0; j < 4; ++j) { dvA[j] = dvB[j]; uuA[j] = uuB[j]; dvB[j] = dvC[j]; uuB[j] = uuC[j]; }
        }
        float pw = 1.f;
#pragma unroll
        for (int n = 0; n < 16; ++n) {
            pw *= p0;
            hf[base + (size_t)n * DIM] = h[n];
            pA[base + (size_t)n * DIM] = pw;
        }
    } else {
        float p[16];
#pragma unroll
        for (int n = 0; n < 16; ++n) p[n] = 1.f;
        for (int l0 = 0; l0 < CHL; l0 += 4) {
            if (l0 + 8 < CHL) {
#pragma unroll
                for (int j = 0; j < 4; ++j) {
                    int row = maprow(k, c * CHL + l0 + 8 + j);
                    dvC[j] = db[(size_t)row * KD * DIM];
                    uuC[j] = ub[(size_t)row * DIM];
                }
            }
#pragma unroll
            for (int j = 0; j < 4; ++j) {
                float du = dvA[j] * uuA[j];
                const float* bl = bs + (l0 + j) * 16;
#pragma unroll
                for (int n = 0; n < 16; ++n) {
                    float dA = __expf(dvA[j] * A[n]);
                    h[n] = dA * h[n] + du * bl[n];
                    p[n] *= dA;
                }
            }
#pragma unroll
            for (int j = 0; j < 4; ++j) { dvA[j] = dvB[j]; uuA[j] = uuB[j]; dvB[j] = dvC[j]; uuB[j] = uuC[j]; }
        }
#pragma unroll
        for (int n = 0; n < 16; ++n) {
            hf[base + (size_t)n * DIM] = h[n];
            pA[base + (size_t)n * DIM] = p[n];
        }
    }
}

// phase B: serial carry combine over chunks; hf[c] overwritten with carry-IN.
__global__ void k_scan_b(float* __restrict__ hf, const float* __restrict__ pA)
{
    int s = blockIdx.x * 256 + threadIdx.x;          // NB*KD*NST*DIM = 49152
    int bk = s / (NST * DIM);
    int r  = s - bk * (NST * DIM);
    size_t base = (size_t)bk * NC * NST * DIM + r;
    const size_t cs = (size_t)NST * DIM;
    float car = 0.f;
#pragma unroll 8
    for (int c = 0; c < NC; ++c) {
        float hfc = hf[base + c * cs], pc = pA[base + c * cs];
        hf[base + c * cs] = car;
        car = pc * car + hfc;
    }
}

// phase C: re-run chunk from carry-in; geometric-A fast path; y pixel-order
// over delta buffer; depth-2 software pipeline; setprio around update.
__global__ void __launch_bounds__(384) k_scan_c(
    const float* __restrict__ unh, const float* __restrict__ CX,
    const float* __restrict__ alog, const float* __restrict__ hf,
    float* __restrict__ dlt)
{
    __shared__ float bs[CHL * 32];
    int b = blockIdx.z, k = blockIdx.y, c = blockIdx.x;
    int d = threadIdx.x;
    for (int i = threadIdx.x; i < CHL * 32; i += 384) {
        int l = i >> 5, n = i & 31;
        int row = maprow(k, c * CHL + l);
        bs[i] = CX[((size_t)(b * LEN) + row) * 192 + k * 48 + 12 + n];
    }
    __syncthreads();

    float A[16], h[16];
    const float* ap = alog + ((size_t)(k * DIM + d)) * NST;
#pragma unroll
    for (int q = 0; q < 4; ++q) {
        float4 av = *(const float4*)(ap + q * 4);
        A[q * 4]     = -__expf(av.x); A[q * 4 + 1] = -__expf(av.y);
        A[q * 4 + 2] = -__expf(av.z); A[q * 4 + 3] = -__expf(av.w);
    }
    bool geo = true;
#pragma unroll
    for (int n = 1; n < 16; ++n)
        geo = geo && (fabsf(A[n] - (n + 1) * A[0]) <= 1e-4f * (n + 1) * fabsf(A[0]));
    size_t base = (((size_t)((b * KD + k) * NC + c)) * NST) * DIM + d;
#pragma unroll
    for (int n = 0; n < 16; ++n) h[n] = hf[base + (size_t)n * DIM];

    const float* ub = unh + (size_t)b * LEN * DIM + d;
    float* db = dlt + ((size_t)(b * LEN) * KD + k) * DIM + d;

    int rowsA[4], rowsB[4], rowsC[4];
    float dvA[4], uuA[4], dvB[4], uuB[4], dvC[4], uuC[4];
#pragma unroll
    for (int j = 0; j < 4; ++j) {
        rowsA[j] = maprow(k, c * CHL + j);
        dvA[j] = db[(size_t)rowsA[j] * KD * DIM];
        uuA[j] = ub[(size_t)rowsA[j] * DIM];
    }
#pragma unroll
    for (int j = 0; j < 4; ++j) {
        rowsB[j] = maprow(k, c * CHL + 4 + j);
        dvB[j] = db[(size_t)rowsB[j] * KD * DIM];
        uuB[j] = ub[(size_t)rowsB[j] * DIM];
    }

    if (geo) {
        float A0 = A[0];
        for (int l0 = 0; l0 < CHL; l0 += 4) {
            if (l0 + 8 < CHL) {
#pragma unroll
                for (int j = 0; j < 4; ++j) {
                    rowsC[j] = maprow(k, c * CHL + l0 + 8 + j);
                    dvC[j] = db[(size_t)rowsC[j] * KD * DIM];
                    uuC[j] = ub[(size_t)rowsC[j] * DIM];
                }
            }
            float ys[4];
            __builtin_amdgcn_s_setprio(1);
#pragma unroll
            for (int j = 0; j < 4; ++j) {
                const float* bl = bs + (l0 + j) * 32;
                float du = dvA[j] * uuA[j];
                float qv = __expf(dvA[j] * A0);
                float pw = qv;
                h[0] = qv * h[0] + du * bl[0];
                float y = h[0] * bl[16];
#pragma unroll
                for (int n = 1; n < 16; ++n) {
                    pw *= qv;
                    h[n] = pw * h[n] + du * bl[n];
                    y += h[n] * bl[16 + n];
                }
                ys[j] = y;
            }
            __builtin_amdgcn_s_setprio(0);
#pragma unroll
            for (int j = 0; j < 4; ++j) db[(size_t)rowsA[j] * KD * DIM] = ys[j];
#pragma unroll
            for (int j = 0; j < 4; ++j) {
                rowsA[j] = rowsB[j]; dvA[j] = dvB[j]; uuA[j] = uuB[j];
                rowsB[j] = rowsC[j]; dvB[j] = dvC[j]; uuB[j] = uuC[j];
            }
        }
    } else {
        for (int l0 = 0; l0 < CHL; l0 += 4) {
            if (l0 + 8 < CHL) {
#pragma unroll
                for (int j = 0; j < 4; ++j) {
                    rowsC[j] = maprow(k, c * CHL + l0 + 8 + j);
                    dvC[j] = db[(size_t)rowsC[j] * KD * DIM];
                    uuC[j] = ub[(size_t)rowsC[j] * DIM];
                }
            }
            float ys[4];
#pragma unroll
            for (int j = 0; j < 4; ++j) {
                const float* bl = bs + (l0 + j) * 32;
                float du = dvA[j] * uuA[j];
                float y = 0.f;
#pragma unroll
                for (int n = 0; n < 16; ++n) {
                    float dA = __expf(dvA[j] * A[n]);
                    h[n] = dA * h[n] + du * bl[n];
                    y += h[n] * bl[16 + n];
                }
                ys[j] = y;
            }
#pragma unroll
            for (int j = 0; j < 4; ++j) db[(size_t)rowsA[j] * KD * DIM] = ys[j];
#pragma unroll
            for (int j = 0; j < 4; ++j) {
                rowsA[j] = rowsB[j]; dvA[j] = dvB[j]; uuA[j] = uuB[j];
                rowsB[j] = rowsC[j]; dvB[j] = dvC[j]; uuB[j] = uuC[j];
            }
        }
    }
}

// ---------------------------------------------------------------------------
// merge 4 directions + D*u + out-LN + silu(z) gate -> yg NHWC (in-place over unh)
__global__ void k_merge(const float* __restrict__ y4, const float* __restrict__ unh,
                        const float* __restrict__ Ds, const float* __restrict__ ong,
                        const float* __restrict__ onb, const float* __restrict__ zt,
                        float* __restrict__ yg)
{
    int lane = threadIdx.x & 63;
    int pix = (blockIdx.x << 2) + (threadIdx.x >> 6);
    const float* yp = y4 + (size_t)pix * KD * DIM;
    const float* up = unh + (size_t)pix * DIM;
    float v[6]; float s = 0.f, ss = 0.f;
#pragma unroll
    for (int j = 0; j < 6; ++j) {
        int d = lane + (j << 6);
        float y = yp[d] + yp[DIM + d] + yp[2 * DIM + d] + yp[3 * DIM + d];
        float dsum = Ds[d] + Ds[DIM + d] + Ds[2 * DIM + d] + Ds[3 * DIM + d];
        y += dsum * up[d];
        v[j] = y; s += y; ss += y * y;
    }
#pragma unroll
    for (int off = 1; off < 64; off <<= 1) { s += __shfl_xor(s, off); ss += __shfl_xor(ss, off); }
    float mu = s * (1.f / 384.f);
    float var = ss * (1.f / 384.f) - mu * mu;
    float rstd = rsqrtf(var + 1e-5f);
    const float* zp = zt + (size_t)pix * DIM;
    float* op = yg + (size_t)pix * DIM;
#pragma unroll
    for (int j = 0; j < 6; ++j) {
        int d = lane + (j << 6);
        float zz = zp[d];
        float gate = zz / (1.f + __expf(-zz));
        op[d] = ((v[j] - mu) * rstd * ong[d] + onb[d]) * gate;
    }
}

// ---------------------------------------------------------------------------
extern "C" void kernel_launch(void* const* d_in, const int* in_sizes, int n_in,
                              void* d_out, int out_size, void* d_ws, size_t ws_size,
                              hipStream_t stream)
{
    const float* x    = (const float*)d_in[0];
    const float* c1w  = (const float*)d_in[1];  const float* c1b = (const float*)d_in[2];
    const float* c2w  = (const float*)d_in[3];  const float* c2b = (const float*)d_in[4];
    const float* c3w  = (const float*)d_in[5];  const float* c3b = (const float*)d_in[6];
    const float* c4w  = (const float*)d_in[7];  const float* c4b = (const float*)d_in[8];
    const float* c5w  = (const float*)d_in[9];  const float* c5b = (const float*)d_in[10];
    const float* ln1g = (const float*)d_in[11]; const float* ln1b= (const float*)d_in[12];
    const float* ipw  = (const float*)d_in[13];
    const float* dww  = (const float*)d_in[14]; const float* dwb = (const float*)d_in[15];
    const float* xpw  = (const float*)d_in[16];
    const float* dtw  = (const float*)d_in[17]; const float* dtb = (const float*)d_in[18];
    const float* alog = (const float*)d_in[19]; const float* dsv = (const float*)d_in[20];
    const float* ong  = (const float*)d_in[21]; const float* onb = (const float*)d_in[22];
    const float* opw  = (const float*)d_in[23];
    float* out = (float*)d_out;

    float* ws   = (float*)d_ws;
    float* FN   = ws;                   // (B*L,192) NHWC feature     1,572,864
    float* XN   = FN   + 1572864;       // PART / CX
    float* XPN  = XN   + 1572864;       // (B*L,384) xp NHWC; PA after dw
    float* ZT   = XPN  + 3145728;       // (B*L,384) z NHWC
    float* XCNH = ZT   + 3145728;       // (B*L,384) u NHWC; yg in-place
    float* DLT  = XCNH + 3145728;       // (B,L,4,384) delta->y; YN after merge
    float* HF   = DLT  + 12582912;      // carries (bk,c,n,d)         3,145,728
    float* WT14 = HF   + 3145728;       // transformed w c1..c4         129,024
    float* WT5  = WT14 + 129024;        // transformed w c5             110,592
    float* WX   = WT5  + 110592;        // padded x_proj_w (192,384)     73,728
    float* MU   = WX   + 73728;         // LN mean (B*L)                  8,192
    float* RS   = MU   + 8192;          // LN rstd (B*L)                  8,192
    // total 28,628,480 floats = 109.2 MiB
    float* PA = XPN;                    // 3,145,728 = NB*KD*NC*NST*DIM exactly
    float* CX = XN;                     // 1,572,864 = NB*LEN*192 exactly
    float* PART = XN;                   // conv partials (stage A & C)
    float* YN = DLT;                    // out_proj output NHWC (B*L,192)

    // weight transforms  (wt layout: (t, co, ci) for MFMA B operand)
    k_wtr<<<dim3(72),  256, 0, stream>>>(c1w, WT14,          64, 32, 9 * 64 * 32);
    k_wtr<<<dim3(108), 256, 0, stream>>>(c2w, WT14 + 18432,  96, 32, 9 * 96 * 32);
    k_wtr<<<dim3(144), 256, 0, stream>>>(c3w, WT14 + 46080, 128, 32, 9 * 128 * 32);
    k_wtr<<<dim3(180), 256, 0, stream>>>(c4w, WT14 + 82944, 160, 32, 9 * 160 * 32);
    k_wtr<<<dim3(432), 256, 0, stream>>>(c5w, WT5,          192, 64, 9 * 192 * 64);
    k_wxp<<<dim3(288), 256, 0, stream>>>(xpw, WX);

    // stage A: dense conv block (MFMA bf16, halo-staged, dy-split)
    k_tr_in<<<dim3(HN, NB), 256, 0, stream>>>(x, FN);
    k_convmf<<<dim3(64, 1, NB * 3), 256, 0, stream>>>(FN, DM, 64, 32, WT14, PART);
    k_ep_nhwc<<<dim3(1024), 256, 0, stream>>>(PART, c1b, FN, 64, 0.01f);
    k_convmf<<<dim3(64, 1, NB * 3), 256, 0, stream>>>(FN, DM, 96, 32, WT14 + 18432, PART);
    k_ep_nhwc<<<dim3(1024), 256, 0, stream>>>(PART, c2b, FN, 96, 0.01f);
    k_convmf<<<dim3(64, 1, NB * 3), 256, 0, stream>>>(FN, DM, 128, 32, WT14 + 46080, PART);
    k_ep_nhwc<<<dim3(1024), 256, 0, stream>>>(PART, c3b, FN, 128, 0.01f);
    k_convmf<<<dim3(64, 1, NB * 3), 256, 0, stream>>>(FN, DM, 160, 32, WT14 + 82944, PART);
    k_ep_nhwc<<<dim3(1024), 256, 0, stream>>>(PART, c4b, FN, 160, 0.01f);

    // stage B: VSS block (MFMA bf16 GEMMs; LN fused into in_proj staging)
    k_lnstat<<<dim3(NB * LEN / 4), 256, 0, stream>>>(FN, MU, RS);
    k_gemm_ipmf<<<dim3(LEN / 64, 12, NB), 256, 0, stream>>>(FN, ipw, ln1g, ln1b, MU, RS, XPN, ZT);
    k_dw<<<dim3(HN, DIM / 64, NB), 256, 0, stream>>>(XPN, dww, dwb, XCNH);
    k_gemm_mf<<<dim3(LEN / 64, 3, NB), 256, 0, stream>>>(XCNH, DIM, WX, nullptr, CX, 192);
    k_delta<<<dim3(LEN / 16, KD, NB), 384, 0, stream>>>(CX, dtw, dtb, DLT);
    k_scan_a<<<dim3(NC, KD, NB), 384, 0, stream>>>(XCNH, CX, alog, DLT, HF, PA);
    k_scan_b<<<dim3(NB * KD * NST * DIM / 256), 256, 0, stream>>>(HF, PA);
    k_scan_c<<<dim3(NC, KD, NB), 384, 0, stream>>>(XCNH, CX, alog, HF, DLT);
    k_merge<<<dim3(NB * LEN / 4), 256, 0, stream>>>(DLT, XCNH, dsv, ong, onb, ZT, XCNH);
    k_gemm_mf<<<dim3(LEN / 64, 3, NB), 256, 0, stream>>>(XCNH, DIM, opw, FN, YN, DM);

    // stage C: final conv (MFMA bf16, NHWC partials + transpose epilogue)
    k_convmf<<<dim3(64, 2, NB * 3), 256, 0, stream>>>(YN, DM, 192, 64, WT5, PART);
    k_ep_pl_tr<<<dim3(64, NB), 256, 0, stream>>>(PART, c5b, out);
}

// Round 22
// 263.651 us; speedup vs baseline: 1.1495x; 1.0143x over previous
//
#include <hip/hip_runtime.h>
#include <hip/hip_bf16.h>
#include <math.h>

// ---- problem constants ----
static constexpr int LEN = 4096;   // H*W
static constexpr int HN  = 64;     // H
static constexpr int WN  = 64;     // W
static constexpr int NB  = 2;      // batch
static constexpr int DM  = 192;    // d_model
static constexpr int DIM = 384;    // d_inner
static constexpr int NST = 16;     // n_state
static constexpr int DTR = 12;     // dt_rank
static constexpr int KD  = 4;      // directions
static constexpr int NC  = 64;     // scan chunks
static constexpr int CHL = LEN / NC; // 64 elements per chunk

typedef __attribute__((ext_vector_type(8))) short bfrag;
typedef __attribute__((ext_vector_type(4))) float facc;

__device__ __forceinline__ unsigned short f2bf(float x) {
    unsigned int u = __float_as_uint(x);
    return (unsigned short)((u + 0x7FFFu + ((u >> 16) & 1u)) >> 16);
}
__device__ __forceinline__ float bf2f(unsigned short u) {
    return __uint_as_float((unsigned int)u << 16);
}

// direction k seq-position -> pixel row index (uniform across a wave)
__device__ __forceinline__ int maprow(int k, int gl) {
    int g = (k & 2) ? (LEN - 1 - gl) : gl;
    return (k & 1) ? (((g & 63) << 6) | (g >> 6)) : g;
}

// ---------------------------------------------------------------------------
// weight transform: w (co,ci,3,3) -> wt (t, co, ci)   [ci contiguous, MFMA B]
__global__ void k_wtr(const float* __restrict__ w, float* __restrict__ wt,
                      int cin, int cout, int n)
{
    int idx = blockIdx.x * 256 + threadIdx.x;
    if (idx >= n) return;
    int ci = idx % cin; int r = idx / cin;
    int co = r % cout; int t = r / cout;
    wt[idx] = w[((size_t)(co * cin + ci)) * 9 + t];
}

// pad x_proj_w (4,44,384) -> WX (192,384), rows k*48+c (c<44), zero pad
__global__ void k_wxp(const float* __restrict__ xpw, float* __restrict__ WX)
{
    int idx = blockIdx.x * 256 + threadIdx.x;    // 192*384
    if (idx >= 192 * DIM) return;
    int row = idx / DIM, d = idx - row * DIM;
    int k = row / 48, c = row - k * 48;
    WX[idx] = (c < 44) ? xpw[((size_t)(k * 44 + c)) * DIM + d] : 0.f;
}

// ---------------------------------------------------------------------------
// x (B,64,L) planar -> FN NHWC cols [0,64)
__global__ void k_tr_in(const float* __restrict__ x, float* __restrict__ FN)
{
    __shared__ float t[64][65];
    int b = blockIdx.y, r = blockIdx.x;
    int tid = threadIdx.x;
#pragma unroll
    for (int i = 0; i < 16; ++i) {
        int idx = (i << 8) + tid;
        int c = idx >> 6, xc = idx & 63;
        t[c][xc] = x[((size_t)(b * 64 + c)) * LEN + r * WN + xc];
    }
    __syncthreads();
#pragma unroll
    for (int i = 0; i < 16; ++i) {
        int idx = (i << 8) + tid;
        int px = idx >> 6, c = idx & 63;
        FN[((size_t)(b * LEN + r * WN + px)) * DM + c] = t[c][px];
    }
}

// ---------------------------------------------------------------------------
// MFMA conv3x3, dy-split partials (NHWC, stride=cout). bf16 halo-staged A;
// wave = 32px x 16oc subtile; 3 dx taps via LDS row shifts.
__global__ void __launch_bounds__(256) k_convmf(
    const float* __restrict__ in, int cbuf, int cin, int cout,
    const float* __restrict__ wt2,
    float* __restrict__ part)
{
    __shared__ unsigned short Asb[66][40];
    __shared__ unsigned short Bsb[3][32][40];
    int zz = blockIdx.z;
    int b = zz / 3, s = zz % 3;
    int y0 = blockIdx.x;
    int n0 = blockIdx.y << 5;
    int tid = threadIdx.x;
    int wv = tid >> 6, lane = tid & 63;
    int mb  = (wv & 1) << 5;
    int nbw = (wv >> 1) << 4;
    int lr = lane & 15, lq = lane >> 4;
    int y = y0 + s - 1;
    bool yok = (unsigned)y < (unsigned)HN;
    const float* inb = in + ((size_t)b * LEN + (size_t)y * WN) * cbuf;

    facc acc0 = (facc){0,0,0,0}, acc1 = (facc){0,0,0,0};

    for (int ci0 = 0; ci0 < cin; ci0 += 32) {
#pragma unroll
        for (int it = 0; it < 3; ++it) {
            int fi = (it << 8) + tid;
            if (fi < 528) {
                int px = fi >> 3, c4 = (fi & 7) << 2;
                int xx = px - 1;
                float4 v = make_float4(0.f, 0.f, 0.f, 0.f);
                if (yok && (unsigned)xx < (unsigned)WN)
                    v = *(const float4*)(inb + (size_t)xx * cbuf + ci0 + c4);
                ushort4 u; u.x = f2bf(v.x); u.y = f2bf(v.y); u.z = f2bf(v.z); u.w = f2bf(v.w);
                *(ushort4*)(&Asb[px][c4]) = u;
            }
        }
#pragma unroll
        for (int it = 0; it < 3; ++it) {
            int fi = (it << 8) + tid;
            int dx = fi >> 8; int rem = fi & 255;
            int oc = rem >> 3, c4 = (rem & 7) << 2;
            int t = s * 3 + dx;
            float4 v = *(const float4*)(wt2 + ((size_t)(t * cout + n0 + oc)) * cin + ci0 + c4);
            ushort4 u; u.x = f2bf(v.x); u.y = f2bf(v.y); u.z = f2bf(v.z); u.w = f2bf(v.w);
            *(ushort4*)(&Bsb[dx][oc][c4]) = u;
        }
        __syncthreads();
#pragma unroll
        for (int dx = 0; dx < 3; ++dx) {
            bfrag a0 = *(const bfrag*)(&Asb[mb + lr + dx][lq * 8]);
            bfrag a1 = *(const bfrag*)(&Asb[mb + 16 + lr + dx][lq * 8]);
            bfrag b0 = *(const bfrag*)(&Bsb[dx][nbw + lr][lq * 8]);
            acc0 = __builtin_amdgcn_mfma_f32_16x16x32_bf16(a0, b0, acc0, 0, 0, 0);
            acc1 = __builtin_amdgcn_mfma_f32_16x16x32_bf16(a1, b0, acc1, 0, 0, 0);
        }
        __syncthreads();
    }
    float* pb = part + (((size_t)(s * NB + b) * LEN) + y0 * WN) * cout + n0 + nbw + lr;
#pragma unroll
    for (int r = 0; r < 4; ++r) {
        int px0 = mb + lq * 4 + r;
        pb[(size_t)px0 * cout] = acc0[r];
        pb[(size_t)(px0 + 16) * cout] = acc1[r];
    }
}

// epilogue: sum 3 dy-partials + bias + leakyrelu -> FN NHWC col block
__global__ void k_ep_nhwc(const float* __restrict__ part, const float* __restrict__ bias,
                          float* __restrict__ FN, int co0, float slope)
{
    int idx = blockIdx.x * 256 + threadIdx.x;
    int co = idx & 31, px = idx >> 5;
    const size_t S = (size_t)NB * LEN * 32;
    float v = part[idx] + part[S + idx] + part[2 * S + idx] + bias[co];
    v = v > 0.f ? v : v * slope;
    FN[(size_t)px * DM + co0 + co] = v;
}

// epilogue c5: partials (s,b,L,64) NHWC -> planar out (B,64,L) via LDS transpose
__global__ void k_ep_pl_tr(const float* __restrict__ part, const float* __restrict__ bias,
                           float* __restrict__ out)
{
    __shared__ float t[64][65];
    int b = blockIdx.y, l0 = blockIdx.x << 6;
    int tid = threadIdx.x;
    const size_t S = (size_t)NB * LEN * 64;
#pragma unroll
    for (int i = 0; i < 16; ++i) {
        int idx = (i << 8) + tid;
        int px = idx >> 6, oc = idx & 63;
        size_t o = ((size_t)b * LEN + l0 + px) * 64 + oc;
        t[px][oc] = part[o] + part[S + o] + part[2 * S + o] + bias[oc];
    }
    __syncthreads();
#pragma unroll
    for (int i = 0; i < 16; ++i) {
        int idx = (i << 8) + tid;
        int oc = idx >> 6, px = idx & 63;
        out[((size_t)(b * 64 + oc)) * LEN + l0 + px] = t[px][oc];
    }
}

// ---------------------------------------------------------------------------
// LN statistics only: per pixel mu and rstd over 192 channels of FN
__global__ void k_lnstat(const float* __restrict__ FN, float* __restrict__ MU,
                         float* __restrict__ RS)
{
    int lane = threadIdx.x & 63;
    int pix  = (blockIdx.x << 2) + (threadIdx.x >> 6);
    const float* fp = FN + (size_t)pix * DM;
    float v0 = fp[lane];
    float v1 = fp[lane + 64];
    float v2 = fp[lane + 128];
    float s = v0 + v1 + v2, ss = v0 * v0 + v1 * v1 + v2 * v2;
#pragma unroll
    for (int off = 1; off < 64; off <<= 1) { s += __shfl_xor(s, off); ss += __shfl_xor(ss, off); }
    if (lane == 0) {
        float mu = s * (1.f / 192.f);
        float var = ss * (1.f / 192.f) - mu * mu;
        MU[pix] = mu;
        RS[pix] = rsqrtf(var + 1e-5f);
    }
}

// ---------------------------------------------------------------------------
// bf16 MFMA GEMM core
struct MfTile { facc a00, a01, a10, a11; int mb, nb, lr, lq; };

__device__ __forceinline__ MfTile mf_gemm_core(
    const float* __restrict__ A, int K, const float* __restrict__ Wt,
    int b, int l0, int n0, unsigned short (*Asb)[72], unsigned short (*Bsb)[72])
{
    int tid = threadIdx.x;
    MfTile t;
    t.a00 = (facc){0,0,0,0}; t.a01 = (facc){0,0,0,0};
    t.a10 = (facc){0,0,0,0}; t.a11 = (facc){0,0,0,0};
    int wv = tid >> 6, lane = tid & 63;
    t.mb = (wv & 1) << 5; t.nb = (wv >> 1) << 5;
    t.lr = lane & 15; t.lq = lane >> 4;

    for (int k0 = 0; k0 < K; k0 += 64) {
#pragma unroll
        for (int s = 0; s < 4; ++s) {
            int idx = (s << 8) + tid;
            int row = idx >> 4, c4 = (idx & 15) << 2;
            float4 av = *(const float4*)(A + ((size_t)b * LEN + l0 + row) * K + k0 + c4);
            ushort4 ua; ua.x = f2bf(av.x); ua.y = f2bf(av.y); ua.z = f2bf(av.z); ua.w = f2bf(av.w);
            *(ushort4*)(&Asb[row][c4]) = ua;
            float4 wvv = *(const float4*)(Wt + (size_t)(n0 + row) * K + k0 + c4);
            ushort4 ub; ub.x = f2bf(wvv.x); ub.y = f2bf(wvv.y); ub.z = f2bf(wvv.z); ub.w = f2bf(wvv.w);
            *(ushort4*)(&Bsb[row][c4]) = ub;
        }
        __syncthreads();
#pragma unroll
        for (int kk = 0; kk < 64; kk += 32) {
            bfrag a0 = *(const bfrag*)(&Asb[t.mb + t.lr][kk + t.lq * 8]);
            bfrag a1 = *(const bfrag*)(&Asb[t.mb + 16 + t.lr][kk + t.lq * 8]);
            bfrag b0 = *(const bfrag*)(&Bsb[t.nb + t.lr][kk + t.lq * 8]);
            bfrag b1 = *(const bfrag*)(&Bsb[t.nb + 16 + t.lr][kk + t.lq * 8]);
            t.a00 = __builtin_amdgcn_mfma_f32_16x16x32_bf16(a0, b0, t.a00, 0, 0, 0);
            t.a01 = __builtin_amdgcn_mfma_f32_16x16x32_bf16(a0, b1, t.a01, 0, 0, 0);
            t.a10 = __builtin_amdgcn_mfma_f32_16x16x32_bf16(a1, b0, t.a10, 0, 0, 0);
            t.a11 = __builtin_amdgcn_mfma_f32_16x16x32_bf16(a1, b1, t.a11, 0, 0, 0);
        }
        __syncthreads();
    }
    return t;
}

__device__ __forceinline__ void mf_store(
    facc v, float* __restrict__ Cp, const float* __restrict__ res,
    int b, int l0, int n0, int outC, int lr, int lq)
{
#pragma unroll
    for (int r = 0; r < 4; ++r) {
        int m = lq * 4 + r, n = lr;
        size_t o = ((size_t)b * LEN + l0 + m) * outC + n0 + n;
        float x = v[r];
        if (res) x += res[o];
        Cp[o] = x;
    }
}

__global__ void __launch_bounds__(256) k_gemm_mf(
    const float* __restrict__ A, int K, const float* __restrict__ Wt,
    const float* __restrict__ res, float* __restrict__ Cp, int outC)
{
    __shared__ unsigned short Asb[64][72];
    __shared__ unsigned short Bsb[64][72];
    int b = blockIdx.z, l0 = blockIdx.x << 6, n0 = blockIdx.y << 6;
    MfTile t = mf_gemm_core(A, K, Wt, b, l0, n0, Asb, Bsb);
    mf_store(t.a00, Cp, res, b, l0 + t.mb,      n0 + t.nb,      outC, t.lr, t.lq);
    mf_store(t.a01, Cp, res, b, l0 + t.mb,      n0 + t.nb + 16, outC, t.lr, t.lq);
    mf_store(t.a10, Cp, res, b, l0 + t.mb + 16, n0 + t.nb,      outC, t.lr, t.lq);
    mf_store(t.a11, Cp, res, b, l0 + t.mb + 16, n0 + t.nb + 16, outC, t.lr, t.lq);
}

// fused LN + in_proj MFMA GEMM: A = raw FN; LN applied during staging.
__global__ void __launch_bounds__(256) k_gemm_ipmf(
    const float* __restrict__ A, const float* __restrict__ Wt,
    const float* __restrict__ g, const float* __restrict__ be,
    const float* __restrict__ MU, const float* __restrict__ RS,
    float* __restrict__ XPN, float* __restrict__ ZT)
{
    __shared__ unsigned short Asb[64][72];
    __shared__ unsigned short Bsb[64][72];
    int b = blockIdx.z, l0 = blockIdx.x << 6, n0 = blockIdx.y << 6;
    int tid = threadIdx.x;
    MfTile t;
    t.a00 = (facc){0,0,0,0}; t.a01 = (facc){0,0,0,0};
    t.a10 = (facc){0,0,0,0}; t.a11 = (facc){0,0,0,0};
    int wv = tid >> 6, lane = tid & 63;
    t.mb = (wv & 1) << 5; t.nb = (wv >> 1) << 5;
    t.lr = lane & 15; t.lq = lane >> 4;

    for (int k0 = 0; k0 < DM; k0 += 64) {
#pragma unroll
        for (int s = 0; s < 4; ++s) {
            int idx = (s << 8) + tid;
            int row = idx >> 4, c4 = (idx & 15) << 2;
            size_t pix = (size_t)b * LEN + l0 + row;
            float4 av = *(const float4*)(A + pix * DM + k0 + c4);
            float mu = MU[pix], rs = RS[pix];
            float4 gv = *(const float4*)(g + k0 + c4);
            float4 bv = *(const float4*)(be + k0 + c4);
            av.x = (av.x - mu) * rs * gv.x + bv.x;
            av.y = (av.y - mu) * rs * gv.y + bv.y;
            av.z = (av.z - mu) * rs * gv.z + bv.z;
            av.w = (av.w - mu) * rs * gv.w + bv.w;
            ushort4 ua; ua.x = f2bf(av.x); ua.y = f2bf(av.y); ua.z = f2bf(av.z); ua.w = f2bf(av.w);
            *(ushort4*)(&Asb[row][c4]) = ua;
            float4 wvv = *(const float4*)(Wt + (size_t)(n0 + row) * DM + k0 + c4);
            ushort4 ub; ub.x = f2bf(wvv.x); ub.y = f2bf(wvv.y); ub.z = f2bf(wvv.z); ub.w = f2bf(wvv.w);
            *(ushort4*)(&Bsb[row][c4]) = ub;
        }
        __syncthreads();
#pragma unroll
        for (int kk = 0; kk < 64; kk += 32) {
            bfrag a0 = *(const bfrag*)(&Asb[t.mb + t.lr][kk + t.lq * 8]);
            bfrag a1 = *(const bfrag*)(&Asb[t.mb + 16 + t.lr][kk + t.lq * 8]);
            bfrag b0 = *(const bfrag*)(&Bsb[t.nb + t.lr][kk + t.lq * 8]);
            bfrag b1 = *(const bfrag*)(&Bsb[t.nb + 16 + t.lr][kk + t.lq * 8]);
            t.a00 = __builtin_amdgcn_mfma_f32_16x16x32_bf16(a0, b0, t.a00, 0, 0, 0);
            t.a01 = __builtin_amdgcn_mfma_f32_16x16x32_bf16(a0, b1, t.a01, 0, 0, 0);
            t.a10 = __builtin_amdgcn_mfma_f32_16x16x32_bf16(a1, b0, t.a10, 0, 0, 0);
            t.a11 = __builtin_amdgcn_mfma_f32_16x16x32_bf16(a1, b1, t.a11, 0, 0, 0);
        }
        __syncthreads();
    }
    float* out = (blockIdx.y < 6) ? XPN : ZT;
    int nc = (blockIdx.y < 6) ? n0 : n0 - DIM;
    mf_store(t.a00, out, nullptr, b, l0 + t.mb,      nc + t.nb,      DIM, t.lr, t.lq);
    mf_store(t.a01, out, nullptr, b, l0 + t.mb,      nc + t.nb + 16, DIM, t.lr, t.lq);
    mf_store(t.a10, out, nullptr, b, l0 + t.mb + 16, nc + t.nb,      DIM, t.lr, t.lq);
    mf_store(t.a11, out, nullptr, b, l0 + t.mb + 16, nc + t.nb + 16, DIM, t.lr, t.lq);
}

// ---------------------------------------------------------------------------
// depthwise conv3x3 + SiLU, NHWC in (XPN) -> NHWC out (unh).
// Rolling 3-column register window: 3 loads per output instead of 9.
__global__ void __launch_bounds__(256) k_dw(
    const float* __restrict__ xpn, const float* __restrict__ w,
    const float* __restrict__ bias, float* __restrict__ unh)
{
    int b = blockIdx.z, cg = blockIdx.y, r = blockIdx.x;
    int lane = threadIdx.x & 63, wv = threadIdx.x >> 6;
    int c = cg * 64 + lane;
    float wl[9];
#pragma unroll
    for (int t = 0; t < 9; ++t) wl[t] = w[c * 9 + t];
    float bv = bias[c];
    const float* base = xpn + (size_t)b * LEN * DIM + c;
    float* ob = unh + (size_t)b * LEN * DIM + c;

    bool top = (r == 0), bot = (r == HN - 1);
    int x0 = wv * 16;

    auto ldcol = [&](int xx, float* v) {
        if ((unsigned)xx < (unsigned)WN) {
            v[0] = top ? 0.f : base[(size_t)((r - 1) * WN + xx) * DIM];
            v[1] = base[(size_t)(r * WN + xx) * DIM];
            v[2] = bot ? 0.f : base[(size_t)((r + 1) * WN + xx) * DIM];
        } else {
            v[0] = 0.f; v[1] = 0.f; v[2] = 0.f;
        }
    };

    float vm1[3], v0[3], vp1[3];
    ldcol(x0 - 1, vm1);
    ldcol(x0, v0);
#pragma unroll
    for (int xi = 0; xi < 16; ++xi) {
        int x = x0 + xi;
        ldcol(x + 1, vp1);
        float acc = bv
            + vm1[0] * wl[0] + v0[0] * wl[1] + vp1[0] * wl[2]
            + vm1[1] * wl[3] + v0[1] * wl[4] + vp1[1] * wl[5]
            + vm1[2] * wl[6] + v0[2] * wl[7] + vp1[2] * wl[8];
        acc = acc / (1.f + __expf(-acc));
        ob[(size_t)(r * WN + x) * DIM] = acc;
#pragma unroll
        for (int dy = 0; dy < 3; ++dy) { vm1[dy] = v0[dy]; v0[dy] = vp1[dy]; }
    }
}

// ---------------------------------------------------------------------------
// delta = softplus(dtb + CX[:, k*48+0..12] @ dtw[k]^T), pixel-order, bf16 out
__global__ void __launch_bounds__(384) k_delta(
    const float* __restrict__ CX, const float* __restrict__ dtw,
    const float* __restrict__ dtb, unsigned short* __restrict__ dlt)
{
    __shared__ float cs[16][12];
    int b = blockIdx.z, k = blockIdx.y;
    int lp0 = blockIdx.x << 4;
    int tid = threadIdx.x;
    if (tid < 192) {
        int p = tid / 12, r = tid - p * 12;
        cs[p][r] = CX[((size_t)(b * LEN) + lp0 + p) * 192 + k * 48 + r];
    }
    __syncthreads();
    float wt[DTR];
    const float* wp = dtw + ((size_t)(k * DIM) + tid) * DTR;
#pragma unroll
    for (int r = 0; r < DTR; ++r) wt[r] = wp[r];
    float bv = dtb[k * DIM + tid];
    unsigned short* dbase = dlt + (((size_t)(b * LEN) + lp0) * KD + k) * DIM + tid;
#pragma unroll
    for (int p = 0; p < 16; ++p) {
        float s = bv;
#pragma unroll
        for (int r = 0; r < DTR; ++r) s += cs[p][r] * wt[r];
        s = (s > 20.f) ? s : __logf(1.f + __expf(s));
        dbase[(size_t)p * KD * DIM] = f2bf(s);
    }
}

// ---------------------------------------------------------------------------
// chunked scan phase A. thread = d; 16 states in registers; geometric-A fast
// path; depth-2 software pipeline on dv/u loads; setprio around update.
// bf16 delta in.
__global__ void __launch_bounds__(384) k_scan_a(
    const float* __restrict__ unh, const float* __restrict__ CX,
    const float* __restrict__ alog, const unsigned short* __restrict__ dlt,
    float* __restrict__ hf, float* __restrict__ pA)
{
    __shared__ float bs[CHL * 16];
    int b = blockIdx.z, k = blockIdx.y, c = blockIdx.x;
    int d = threadIdx.x;
    for (int i = threadIdx.x; i < CHL * 16; i += 384) {
        int l = i >> 4, n = i & 15;
        int row = maprow(k, c * CHL + l);
        bs[i] = CX[((size_t)(b * LEN) + row) * 192 + k * 48 + 12 + n];
    }
    __syncthreads();

    float A[16], h[16];
    const float* ap = alog + ((size_t)(k * DIM + d)) * NST;
#pragma unroll
    for (int q = 0; q < 4; ++q) {
        float4 av = *(const float4*)(ap + q * 4);
        A[q * 4]     = -__expf(av.x); A[q * 4 + 1] = -__expf(av.y);
        A[q * 4 + 2] = -__expf(av.z); A[q * 4 + 3] = -__expf(av.w);
    }
    bool geo = true;
#pragma unroll
    for (int n = 1; n < 16; ++n)
        geo = geo && (fabsf(A[n] - (n + 1) * A[0]) <= 1e-4f * (n + 1) * fabsf(A[0]));
#pragma unroll
    for (int n = 0; n < 16; ++n) h[n] = 0.f;

    const float* ub = unh + (size_t)b * LEN * DIM + d;
    const unsigned short* db = dlt + ((size_t)(b * LEN) * KD + k) * DIM + d;
    size_t base = (((size_t)((b * KD + k) * NC + c)) * NST) * DIM + d;

    float dvA[4], uuA[4], dvB[4], uuB[4], dvC[4], uuC[4];
#pragma unroll
    for (int j = 0; j < 4; ++j) {
        int row = maprow(k, c * CHL + j);
        dvA[j] = bf2f(db[(size_t)row * KD * DIM]);
        uuA[j] = ub[(size_t)row * DIM];
    }
#pragma unroll
    for (int j = 0; j < 4; ++j) {
        int row = maprow(k, c * CHL + 4 + j);
        dvB[j] = bf2f(db[(size_t)row * KD * DIM]);
        uuB[j] = ub[(size_t)row * DIM];
    }

    if (geo) {
        float A0 = A[0];
        float p0 = 1.f;
        for (int l0 = 0; l0 < CHL; l0 += 4) {
            if (l0 + 8 < CHL) {
#pragma unroll
                for (int j = 0; j < 4; ++j) {
                    int row = maprow(k, c * CHL + l0 + 8 + j);
                    dvC[j] = bf2f(db[(size_t)row * KD * DIM]);
                    uuC[j] = ub[(size_t)row * DIM];
                }
            }
            __builtin_amdgcn_s_setprio(1);
#pragma unroll
            for (int j = 0; j < 4; ++j) {
                float du = dvA[j] * uuA[j];
                const float* bl = bs + (l0 + j) * 16;
                float qv = __expf(dvA[j] * A0);
                float pw = qv;
                h[0] = qv * h[0] + du * bl[0];
#pragma unroll
                for (int n = 1; n < 16; ++n) { pw *= qv; h[n] = pw * h[n] + du * bl[n]; }
                p0 *= qv;
            }
            __builtin_amdgcn_s_setprio(0);
#pragma unroll
            for (int j = 0; j < 4; ++j) { dvA[j] = dvB[j]; uuA[j] = uuB[j]; dvB[j] = dvC[j]; uuB[j] = uuC[j]; }
        }
        float pw = 1.f;
#pragma unroll
        for (int n = 0; n < 16; ++n) {
            pw *= p0;
            hf[base + (size_t)n * DIM] = h[n];
            pA[base + (size_t)n * DIM] = pw;
        }
    } else {
        float p[16];
#pragma unroll
        for (int n = 0; n < 16; ++n) p[n] = 1.f;
        for (int l0 = 0; l0 < CHL; l0 += 4) {
            if (l0 + 8 < CHL) {
#pragma unroll
                for (int j = 0; j < 4; ++j) {
                    int row = maprow(k, c * CHL + l0 + 8 + j);
                    dvC[j] = bf2f(db[(size_t)row * KD * DIM]);
                    uuC[j] = ub[(size_t)row * DIM];
                }
            }
#pragma unroll
            for (int j = 0; j < 4; ++j) {
                float du = dvA[j] * uuA[j];
                const float* bl = bs + (l0 + j) * 16;
#pragma unroll
                for (int n = 0; n < 16; ++n) {
                    float dA = __expf(dvA[j] * A[n]);
                    h[n] = dA * h[n] + du * bl[n];
                    p[n] *= dA;
                }
            }
#pragma unroll
            for (int j = 0; j < 4; ++j) { dvA[j] = dvB[j]; uuA[j] = uuB[j]; dvB[j] = dvC[j]; uuB[j] = uuC[j]; }
        }
#pragma unroll
        for (int n = 0; n < 16; ++n) {
            hf[base + (size_t)n * DIM] = h[n];
            pA[base + (size_t)n * DIM] = p[n];
        }
    }
}

// phase B: serial carry combine over chunks; hf[c] overwritten with carry-IN.
__global__ void k_scan_b(float* __restrict__ hf, const float* __restrict__ pA)
{
    int s = blockIdx.x * 256 + threadIdx.x;          // NB*KD*NST*DIM = 49152
    int bk = s / (NST * DIM);
    int r  = s - bk * (NST * DIM);
    size_t base = (size_t)bk * NC * NST * DIM + r;
    const size_t cs = (size_t)NST * DIM;
    float car = 0.f;
#pragma unroll 8
    for (int c = 0; c < NC; ++c) {
        float hfc = hf[base + c * cs], pc = pA[base + c * cs];
        hf[base + c * cs] = car;
        car = pc * car + hfc;
    }
}

// phase C: re-run chunk from carry-in; geometric-A fast path; bf16 delta in,
// bf16 y out (in-place over delta buffer); depth-2 pipeline; setprio.
__global__ void __launch_bounds__(384) k_scan_c(
    const float* __restrict__ unh, const float* __restrict__ CX,
    const float* __restrict__ alog, const float* __restrict__ hf,
    unsigned short* __restrict__ dlt)
{
    __shared__ float bs[CHL * 32];
    int b = blockIdx.z, k = blockIdx.y, c = blockIdx.x;
    int d = threadIdx.x;
    for (int i = threadIdx.x; i < CHL * 32; i += 384) {
        int l = i >> 5, n = i & 31;
        int row = maprow(k, c * CHL + l);
        bs[i] = CX[((size_t)(b * LEN) + row) * 192 + k * 48 + 12 + n];
    }
    __syncthreads();

    float A[16], h[16];
    const float* ap = alog + ((size_t)(k * DIM + d)) * NST;
#pragma unroll
    for (int q = 0; q < 4; ++q) {
        float4 av = *(const float4*)(ap + q * 4);
        A[q * 4]     = -__expf(av.x); A[q * 4 + 1] = -__expf(av.y);
        A[q * 4 + 2] = -__expf(av.z); A[q * 4 + 3] = -__expf(av.w);
    }
    bool geo = true;
#pragma unroll
    for (int n = 1; n < 16; ++n)
        geo = geo && (fabsf(A[n] - (n + 1) * A[0]) <= 1e-4f * (n + 1) * fabsf(A[0]));
    size_t base = (((size_t)((b * KD + k) * NC + c)) * NST) * DIM + d;
#pragma unroll
    for (int n = 0; n < 16; ++n) h[n] = hf[base + (size_t)n * DIM];

    const float* ub = unh + (size_t)b * LEN * DIM + d;
    unsigned short* db = dlt + ((size_t)(b * LEN) * KD + k) * DIM + d;

    int rowsA[4], rowsB[4], rowsC[4];
    float dvA[4], uuA[4], dvB[4], uuB[4], dvC[4], uuC[4];
#pragma unroll
    for (int j = 0; j < 4; ++j) {
        rowsA[j] = maprow(k, c * CHL + j);
        dvA[j] = bf2f(db[(size_t)rowsA[j] * KD * DIM]);
        uuA[j] = ub[(size_t)rowsA[j] * DIM];
    }
#pragma unroll
    for (int j = 0; j < 4; ++j) {
        rowsB[j] = maprow(k, c * CHL + 4 + j);
        dvB[j] = bf2f(db[(size_t)rowsB[j] * KD * DIM]);
        uuB[j] = ub[(size_t)rowsB[j] * DIM];
    }

    if (geo) {
        float A0 = A[0];
        for (int l0 = 0; l0 < CHL; l0 += 4) {
            if (l0 + 8 < CHL) {
#pragma unroll
                for (int j = 0; j < 4; ++j) {
                    rowsC[j] = maprow(k, c * CHL + l0 + 8 + j);
                    dvC[j] = bf2f(db[(size_t)rowsC[j] * KD * DIM]);
                    uuC[j] = ub[(size_t)rowsC[j] * DIM];
                }
            }
            float ys[4];
            __builtin_amdgcn_s_setprio(1);
#pragma unroll
            for (int j = 0; j < 4; ++j) {
                const float* bl = bs + (l0 + j) * 32;
                float du = dvA[j] * uuA[j];
                float qv = __expf(dvA[j] * A0);
                float pw = qv;
                h[0] = qv * h[0] + du * bl[0];
                float y = h[0] * bl[16];
#pragma unroll
                for (int n = 1; n < 16; ++n) {
                    pw *= qv;
                    h[n] = pw * h[n] + du * bl[n];
                    y += h[n] * bl[16 + n];
                }
                ys[j] = y;
            }
            __builtin_amdgcn_s_setprio(0);
#pragma unroll
            for (int j = 0; j < 4; ++j) db[(size_t)rowsA[j] * KD * DIM] = f2bf(ys[j]);
#pragma unroll
            for (int j = 0; j < 4; ++j) {
                rowsA[j] = rowsB[j]; dvA[j] = dvB[j]; uuA[j] = uuB[j];
                rowsB[j] = rowsC[j]; dvB[j] = dvC[j]; uuB[j] = uuC[j];
            }
        }
    } else {
        for (int l0 = 0; l0 < CHL; l0 += 4) {
            if (l0 + 8 < CHL) {
#pragma unroll
                for (int j = 0; j < 4; ++j) {
                    rowsC[j] = maprow(k, c * CHL + l0 + 8 + j);
                    dvC[j] = bf2f(db[(size_t)rowsC[j] * KD * DIM]);
                    uuC[j] = ub[(size_t)rowsC[j] * DIM];
                }
            }
            float ys[4];
#pragma unroll
            for (int j = 0; j < 4; ++j) {
                const float* bl = bs + (l0 + j) * 32;
                float du = dvA[j] * uuA[j];
                float y = 0.f;
#pragma unroll
                for (int n = 0; n < 16; ++n) {
                    float dA = __expf(dvA[j] * A[n]);
                    h[n] = dA * h[n] + du * bl[n];
                    y += h[n] * bl[16 + n];
                }
                ys[j] = y;
            }
#pragma unroll
            for (int j = 0; j < 4; ++j) db[(size_t)rowsA[j] * KD * DIM] = f2bf(ys[j]);
#pragma unroll
            for (int j = 0; j < 4; ++j) {
                rowsA[j] = rowsB[j]; dvA[j] = dvB[j]; uuA[j] = uuB[j];
                rowsB[j] = rowsC[j]; dvB[j] = dvC[j]; uuB[j] = uuC[j];
            }
        }
    }
}

// ---------------------------------------------------------------------------
// merge 4 directions (bf16 y) + D*u + out-LN + silu(z) gate -> yg NHWC
__global__ void k_merge(const unsigned short* __restrict__ y4, const float* __restrict__ unh,
                        const float* __restrict__ Ds, const float* __restrict__ ong,
                        const float* __restrict__ onb, const float* __restrict__ zt,
                        float* __restrict__ yg)
{
    int lane = threadIdx.x & 63;
    int pix = (blockIdx.x << 2) + (threadIdx.x >> 6);
    const unsigned short* yp = y4 + (size_t)pix * KD * DIM;
    const float* up = unh + (size_t)pix * DIM;
    float v[6]; float s = 0.f, ss = 0.f;
#pragma unroll
    for (int j = 0; j < 6; ++j) {
        int d = lane + (j << 6);
        float y = bf2f(yp[d]) + bf2f(yp[DIM + d]) + bf2f(yp[2 * DIM + d]) + bf2f(yp[3 * DIM + d]);
        float dsum = Ds[d] + Ds[DIM + d] + Ds[2 * DIM + d] + Ds[3 * DIM + d];
        y += dsum * up[d];
        v[j] = y; s += y; ss += y * y;
    }
#pragma unroll
    for (int off = 1; off < 64; off <<= 1) { s += __shfl_xor(s, off); ss += __shfl_xor(ss, off); }
    float mu = s * (1.f / 384.f);
    float var = ss * (1.f / 384.f) - mu * mu;
    float rstd = rsqrtf(var + 1e-5f);
    const float* zp = zt + (size_t)pix * DIM;
    float* op = yg + (size_t)pix * DIM;
#pragma unroll
    for (int j = 0; j < 6; ++j) {
        int d = lane + (j << 6);
        float zz = zp[d];
        float gate = zz / (1.f + __expf(-zz));
        op[d] = ((v[j] - mu) * rstd * ong[d] + onb[d]) * gate;
    }
}

// ---------------------------------------------------------------------------
extern "C" void kernel_launch(void* const* d_in, const int* in_sizes, int n_in,
                              void* d_out, int out_size, void* d_ws, size_t ws_size,
                              hipStream_t stream)
{
    const float* x    = (const float*)d_in[0];
    const float* c1w  = (const float*)d_in[1];  const float* c1b = (const float*)d_in[2];
    const float* c2w  = (const float*)d_in[3];  const float* c2b = (const float*)d_in[4];
    const float* c3w  = (const float*)d_in[5];  const float* c3b = (const float*)d_in[6];
    const float* c4w  = (const float*)d_in[7];  const float* c4b = (const float*)d_in[8];
    const float* c5w  = (const float*)d_in[9];  const float* c5b = (const float*)d_in[10];
    const float* ln1g = (const float*)d_in[11]; const float* ln1b= (const float*)d_in[12];
    const float* ipw  = (const float*)d_in[13];
    const float* dww  = (const float*)d_in[14]; const float* dwb = (const float*)d_in[15];
    const float* xpw  = (const float*)d_in[16];
    const float* dtw  = (const float*)d_in[17]; const float* dtb = (const float*)d_in[18];
    const float* alog = (const float*)d_in[19]; const float* dsv = (const float*)d_in[20];
    const float* ong  = (const float*)d_in[21]; const float* onb = (const float*)d_in[22];
    const float* opw  = (const float*)d_in[23];
    float* out = (float*)d_out;

    float* ws   = (float*)d_ws;
    float* FN   = ws;                   // (B*L,192) NHWC feature     1,572,864
    float* XN   = FN   + 1572864;       // PART / CX
    float* XPN  = XN   + 1572864;       // (B*L,384) xp NHWC; PA after dw
    float* ZT   = XPN  + 3145728;       // (B*L,384) z NHWC
    float* XCNH = ZT   + 3145728;       // (B*L,384) u NHWC; yg in-place
    float* DLT  = XCNH + 3145728;       // bf16 delta->y (B,L,4,384); YN after merge
    float* HF   = DLT  + 12582912;      // carries (bk,c,n,d)         3,145,728
    float* WT14 = HF   + 3145728;       // transformed w c1..c4         129,024
    float* WT5  = WT14 + 129024;        // transformed w c5             110,592
    float* WX   = WT5  + 110592;        // padded x_proj_w (192,384)     73,728
    float* MU   = WX   + 73728;         // LN mean (B*L)                  8,192
    float* RS   = MU   + 8192;          // LN rstd (B*L)                  8,192
    // total 28,628,480 floats = 109.2 MiB
    unsigned short* DLTB = (unsigned short*)DLT;
    float* PA = XPN;                    // 3,145,728 = NB*KD*NC*NST*DIM exactly
    float* CX = XN;                     // 1,572,864 = NB*LEN*192 exactly
    float* PART = XN;                   // conv partials (stage A & C)
    float* YN = DLT;                    // out_proj output NHWC (B*L,192)

    // weight transforms  (wt layout: (t, co, ci) for MFMA B operand)
    k_wtr<<<dim3(72),  256, 0, stream>>>(c1w, WT14,          64, 32, 9 * 64 * 32);
    k_wtr<<<dim3(108), 256, 0, stream>>>(c2w, WT14 + 18432,  96, 32, 9 * 96 * 32);
    k_wtr<<<dim3(144), 256, 0, stream>>>(c3w, WT14 + 46080, 128, 32, 9 * 128 * 32);
    k_wtr<<<dim3(180), 256, 0, stream>>>(c4w, WT14 + 82944, 160, 32, 9 * 160 * 32);
    k_wtr<<<dim3(432), 256, 0, stream>>>(c5w, WT5,          192, 64, 9 * 192 * 64);
    k_wxp<<<dim3(288), 256, 0, stream>>>(xpw, WX);

    // stage A: dense conv block (MFMA bf16, halo-staged, dy-split)
    k_tr_in<<<dim3(HN, NB), 256, 0, stream>>>(x, FN);
    k_convmf<<<dim3(64, 1, NB * 3), 256, 0, stream>>>(FN, DM, 64, 32, WT14, PART);
    k_ep_nhwc<<<dim3(1024), 256, 0, stream>>>(PART, c1b, FN, 64, 0.01f);
    k_convmf<<<dim3(64, 1, NB * 3), 256, 0, stream>>>(FN, DM, 96, 32, WT14 + 18432, PART);
    k_ep_nhwc<<<dim3(1024), 256, 0, stream>>>(PART, c2b, FN, 96, 0.01f);
    k_convmf<<<dim3(64, 1, NB * 3), 256, 0, stream>>>(FN, DM, 128, 32, WT14 + 46080, PART);
    k_ep_nhwc<<<dim3(1024), 256, 0, stream>>>(PART, c3b, FN, 128, 0.01f);
    k_convmf<<<dim3(64, 1, NB * 3), 256, 0, stream>>>(FN, DM, 160, 32, WT14 + 82944, PART);
    k_ep_nhwc<<<dim3(1024), 256, 0, stream>>>(PART, c4b, FN, 160, 0.01f);

    // stage B: VSS block (MFMA bf16 GEMMs; LN fused; bf16 delta/y scan path)
    k_lnstat<<<dim3(NB * LEN / 4), 256, 0, stream>>>(FN, MU, RS);
    k_gemm_ipmf<<<dim3(LEN / 64, 12, NB), 256, 0, stream>>>(FN, ipw, ln1g, ln1b, MU, RS, XPN, ZT);
    k_dw<<<dim3(HN, DIM / 64, NB), 256, 0, stream>>>(XPN, dww, dwb, XCNH);
    k_gemm_mf<<<dim3(LEN / 64, 3, NB), 256, 0, stream>>>(XCNH, DIM, WX, nullptr, CX, 192);
    k_delta<<<dim3(LEN / 16, KD, NB), 384, 0, stream>>>(CX, dtw, dtb, DLTB);
    k_scan_a<<<dim3(NC, KD, NB), 384, 0, stream>>>(XCNH, CX, alog, DLTB, HF, PA);
    k_scan_b<<<dim3(NB * KD * NST * DIM / 256), 256, 0, stream>>>(HF, PA);
    k_scan_c<<<dim3(NC, KD, NB), 384, 0, stream>>>(XCNH, CX, alog, HF, DLTB);
    k_merge<<<dim3(NB * LEN / 4), 256, 0, stream>>>(DLTB, XCNH, dsv, ong, onb, ZT, XCNH);
    k_gemm_mf<<<dim3(LEN / 64, 3, NB), 256, 0, stream>>>(XCNH, DIM, opw, FN, YN, DM);

    // stage C: final conv (MFMA bf16, NHWC partials + transpose epilogue)
    k_convmf<<<dim3(64, 2, NB * 3), 256, 0, stream>>>(YN, DM, 192, 64, WT5, PART);
    k_ep_pl_tr<<<dim3(64, NB), 256, 0, stream>>>(PART, c5b, out);
}